// Round 1
// baseline (1743.794 us; speedup 1.0000x reference)
//
#include <hip/hip_runtime.h>

#define NN 50000
#define FD 128
#define NE 800000
#define NG 512
#define NC 16
#define NL 3
#define NTOT 100000
#define BNEPS 1e-5f
#define LOGITS_N (NL*NG*NC)

// ---- workspace layout (bytes), all offsets 512-aligned ----
#define OFF_DEG      0ul          // 100000 int
#define OFF_GCNT     400384ul     // 2*512 int
#define MEMSET_BYTES 404480ul     // covers DEG + GCNT
#define OFF_ROWPTR   409600ul     // 100001 int
#define OFF_CURSOR   819200ul     // 100000 int
#define OFF_USTART   1228800ul    // 513 int
#define OFF_ISTART   1231872ul    // 513 int
#define OFF_INVCNT   1234944ul    // 512 f32
#define OFF_BNPART   1238016ul    // 2*2*196*128 f32
#define OFF_BNSC     2048000ul    // 256 f32
#define OFF_BNSH     2049024ul    // 256 f32
#define OFF_WT       2050048ul    // 6*256*128 f32
#define OFF_CSR      2836480ul    // 1600000 int
#define OFF_AGGI     9236480ul    // 50000*128 f32 (becomes new_i in-place)
#define OFF_AGGU     34836480ul   // 50000*128 f32 (becomes new_u in-place)
#define OFF_XU       60436480ul   // 50000*128 f32
#define OFF_XI       86036480ul   // 50000*128 f32

__global__ __launch_bounds__(256) void k_hist_edges(const int* __restrict__ eu2i,
                                                    const int* __restrict__ ei2u,
                                                    int* __restrict__ deg) {
  int idx = blockIdx.x*256 + threadIdx.x;
  if (idx >= 2*NE) return;
  int rel = idx >= NE;
  int e = rel ? idx - NE : idx;
  const int* edge = rel ? ei2u : eu2i;
  int dst = edge[NE + e];
  atomicAdd(&deg[rel ? NN + dst : dst], 1);
}

__global__ __launch_bounds__(256) void k_hist_batch(const int* __restrict__ bu,
                                                    const int* __restrict__ bi,
                                                    int* __restrict__ gcnt) {
  int i = blockIdx.x*256 + threadIdx.x;
  if (i >= NTOT) return;
  int type = i >= NN;
  int g = type ? bi[i-NN] : bu[i];
  atomicAdd(&gcnt[type*NG + g], 1);
}

__global__ __launch_bounds__(1024) void k_scan_big(const int* __restrict__ deg,
                                                   int* __restrict__ rowptr,
                                                   int* __restrict__ cursor) {
  __shared__ int part[1024];
  int t = threadIdx.x;
  const int CH = 98;                       // 1024*98 >= 100000
  int base = t*CH;
  int s = 0;
  for (int i = 0; i < CH; i++) { int idx = base+i; if (idx < NTOT) s += deg[idx]; }
  part[t] = s;
  __syncthreads();
  for (int off = 1; off < 1024; off <<= 1) {
    int v = (t >= off) ? part[t-off] : 0;
    __syncthreads();
    part[t] += v;
    __syncthreads();
  }
  int run = (t == 0) ? 0 : part[t-1];
  for (int i = 0; i < CH; i++) {
    int idx = base+i;
    if (idx < NTOT) { rowptr[idx] = run; cursor[idx] = run; run += deg[idx]; }
  }
  if (t == 1023) rowptr[NTOT] = part[1023];
}

__global__ __launch_bounds__(512) void k_scan_g(const int* __restrict__ gcnt,
                                                int* __restrict__ ustart,
                                                int* __restrict__ istart,
                                                float* __restrict__ invcnt) {
  __shared__ int pu[512], pi[512];
  int t = threadIdx.x;
  int cu = gcnt[t], ci = gcnt[NG + t];
  pu[t] = cu; pi[t] = ci;
  __syncthreads();
  for (int off = 1; off < 512; off <<= 1) {
    int vu = (t >= off) ? pu[t-off] : 0;
    int vi = (t >= off) ? pi[t-off] : 0;
    __syncthreads();
    pu[t] += vu; pi[t] += vi;
    __syncthreads();
  }
  ustart[t] = pu[t] - cu;
  istart[t] = pi[t] - ci;
  if (t == 511) { ustart[NG] = pu[511]; istart[NG] = pi[511]; }
  int c = cu + ci;
  invcnt[t] = 1.0f / (float)(c > 0 ? c : 1);
}

__global__ __launch_bounds__(256) void k_fill_csr(const int* __restrict__ eu2i,
                                                  const int* __restrict__ ei2u,
                                                  int* __restrict__ cursor,
                                                  int* __restrict__ csr) {
  int idx = blockIdx.x*256 + threadIdx.x;
  if (idx >= 2*NE) return;
  int rel = idx >= NE;
  int e = rel ? idx - NE : idx;
  const int* edge = rel ? ei2u : eu2i;
  int src = edge[e];
  int dst = edge[NE + e];
  int pos = atomicAdd(&cursor[rel ? NN + dst : dst], 1);
  csr[pos] = src;
}

// WT[lr][k][h]: k<128 -> Wrel[l][h][k], k>=128 -> Wroot[l][h][k-128]
__global__ __launch_bounds__(256) void k_transposeW(
    const float* __restrict__ WrelA, const float* __restrict__ WrootA,
    const float* __restrict__ WrelB, const float* __restrict__ WrootB,
    float* __restrict__ WT) {
  int idx = blockIdx.x*256 + threadIdx.x;   // < 6*32768
  int lr = idx >> 15;
  int rem = idx & 32767;
  int k = rem >> 7;
  int h = rem & 127;
  int l = lr >> 1;
  int rel = lr & 1;
  const float* Wr = rel ? WrelB : WrelA;
  const float* Wo = rel ? WrootB : WrootA;
  float v = (k < FD) ? Wr[(l*FD + h)*FD + k] : Wo[(l*FD + h)*FD + (k-FD)];
  WT[idx] = v;
}

// one wave per destination row; 2 independent accumulation chains for ILP
__global__ __launch_bounds__(256) void k_gather(const float* __restrict__ src,
                                                const int* __restrict__ rowptr,
                                                const int* __restrict__ csr,
                                                float* __restrict__ out,
                                                int slotbase) {
  int row = blockIdx.x*4 + (threadIdx.x >> 6);
  if (row >= NN) return;
  int lane = threadIdx.x & 63;
  int p = rowptr[slotbase + row];
  int pe = rowptr[slotbase + row + 1];
  float2 a0 = make_float2(0.f,0.f), a1 = make_float2(0.f,0.f);
  for (; p+2 <= pe; p += 2) {
    int s0 = csr[p], s1 = csr[p+1];
    float2 v0 = *(const float2*)(src + (size_t)s0*FD + lane*2);
    float2 v1 = *(const float2*)(src + (size_t)s1*FD + lane*2);
    a0.x += v0.x; a0.y += v0.y;
    a1.x += v1.x; a1.y += v1.y;
  }
  if (p < pe) {
    int s0 = csr[p];
    float2 v0 = *(const float2*)(src + (size_t)s0*FD + lane*2);
    a0.x += v0.x; a0.y += v0.y;
  }
  a0.x += a1.x; a0.y += a1.y;
  *(float2*)(out + (size_t)row*FD + lane*2) = a0;
}

// new[n,h] = sum_k A1[n,k]*WT[k][h] (k<128) + A2[n,k-128]*WT[k][h] (k>=128) + bias[h]
// out == A1 is safe: a block's A1 reads all complete (barriered) before its stores.
__global__ __launch_bounds__(256) void k_gemm(const float* __restrict__ A1,
                                              const float* __restrict__ A2,
                                              const float* __restrict__ WT,
                                              const float* __restrict__ bias,
                                              float* __restrict__ out) {
  __shared__ float As[16][128];
  __shared__ float Bs[16][128];
  int tid = threadIdx.x;
  int n0 = blockIdx.x * 128;
  int tn = (tid & 15) * 8;
  int th = (tid >> 4) * 8;
  float acc[8][8];
  #pragma unroll
  for (int i=0;i<8;i++)
    #pragma unroll
    for (int j=0;j<8;j++) acc[i][j] = 0.f;

  for (int k0 = 0; k0 < 256; k0 += 16) {
    const float* Asrc = (k0 < FD) ? (A1 + k0) : (A2 + (k0 - FD));
    #pragma unroll
    for (int i = 0; i < 2; i++) {
      int idx = tid + i*256;
      int row = idx >> 2;
      int kq = (idx & 3) * 4;
      float4 v = make_float4(0.f,0.f,0.f,0.f);
      int r = n0 + row;
      if (r < NN) v = *(const float4*)(Asrc + (size_t)r*FD + kq);
      As[kq+0][row] = v.x; As[kq+1][row] = v.y; As[kq+2][row] = v.z; As[kq+3][row] = v.w;
    }
    #pragma unroll
    for (int i = 0; i < 2; i++) {
      int idx = tid + i*256;
      int kk = idx >> 5;
      int h4 = (idx & 31) * 4;
      *(float4*)&Bs[kk][h4] = *(const float4*)(WT + (size_t)(k0+kk)*FD + h4);
    }
    __syncthreads();
    #pragma unroll
    for (int k = 0; k < 16; k++) {
      float a[8], b[8];
      *(float4*)&a[0] = *(const float4*)&As[k][tn];
      *(float4*)&a[4] = *(const float4*)&As[k][tn+4];
      *(float4*)&b[0] = *(const float4*)&Bs[k][th];
      *(float4*)&b[4] = *(const float4*)&Bs[k][th+4];
      #pragma unroll
      for (int i=0;i<8;i++)
        #pragma unroll
        for (int j=0;j<8;j++)
          acc[i][j] = fmaf(a[i], b[j], acc[i][j]);
    }
    __syncthreads();
  }
  float bj[8];
  #pragma unroll
  for (int j=0;j<8;j++) bj[j] = bias[th+j];
  #pragma unroll
  for (int i=0;i<8;i++) {
    int r = n0 + tn + i;
    if (r < NN) {
      #pragma unroll
      for (int j=0;j<8;j++) acc[i][j] += bj[j];
      *(float4*)(out + (size_t)r*FD + th) = *(float4*)&acc[i][0];
      *(float4*)(out + (size_t)r*FD + th + 4) = *(float4*)&acc[i][4];
    }
  }
}

// per-block partial sums of relu(new) and relu(new)^2 per column (no atomics)
__global__ __launch_bounds__(128) void k_stats(const float* __restrict__ newU,
                                               const float* __restrict__ newI,
                                               float* __restrict__ psum,
                                               float* __restrict__ psq) {
  int type = blockIdx.y;
  const float* in = type ? newI : newU;
  int c = threadIdx.x;
  int r0 = blockIdx.x * 256;
  float s = 0.f, s2 = 0.f;
  for (int i = 0; i < 256; i++) {
    int r = r0 + i;
    if (r < NN) {
      float y = in[(size_t)r*FD + c];
      y = y > 0.f ? y : 0.f;
      s += y; s2 += y*y;
    }
  }
  int o = (type*196 + blockIdx.x)*FD + c;
  psum[o] = s; psq[o] = s2;
}

__global__ __launch_bounds__(256) void k_bnfinal(const float* __restrict__ psum,
                                                 const float* __restrict__ psq,
                                                 const float* __restrict__ gu,
                                                 const float* __restrict__ bu,
                                                 const float* __restrict__ gi,
                                                 const float* __restrict__ bi,
                                                 float* __restrict__ bnsc,
                                                 float* __restrict__ bnsh) {
  int tid = threadIdx.x;
  int type = tid >> 7;
  int c = tid & 127;
  float s = 0.f, s2 = 0.f;
  for (int b = 0; b < 196; b++) {
    int o = (type*196 + b)*FD + c;
    s += psum[o]; s2 += psq[o];
  }
  float inv = 1.0f / (float)NN;
  float mean = s * inv;
  float var = s2 * inv - mean*mean;
  float rstd = rsqrtf(var + BNEPS);
  float g = type ? gi[c] : gu[c];
  float bb = type ? bi[c] : bu[c];
  float sc = rstd * g;
  bnsc[tid] = sc;
  bnsh[tid] = bb - mean * sc;
}

__global__ __launch_bounds__(256) void k_bnapply(const float* __restrict__ newU,
                                                 const float* __restrict__ newI,
                                                 const float* __restrict__ bnsc,
                                                 const float* __restrict__ bnsh,
                                                 float* __restrict__ xu,
                                                 float* __restrict__ xi) {
  int type = blockIdx.y;
  const float* in = type ? newI : newU;
  float* out = type ? xi : xu;
  int tid = threadIdx.x;
  int c = tid & 127;
  int rh = tid >> 7;
  float sc = bnsc[type*128 + c];
  float sh = bnsh[type*128 + c];
  int base = blockIdx.x * 128;
  for (int i = 0; i < 64; i++) {
    int r = base + i*2 + rh;
    if (r < NN) {
      float y = in[(size_t)r*FD + c];
      y = y > 0.f ? y : 0.f;
      out[(size_t)r*FD + c] = y * sc + sh;
    }
  }
}

// one block per graph; batch ids are sorted so each graph is a contiguous row range
__global__ __launch_bounds__(256) void k_pool(const float* __restrict__ xu,
                                              const float* __restrict__ xi,
                                              const int* __restrict__ ustart,
                                              const int* __restrict__ istart,
                                              const float* __restrict__ invcnt,
                                              float* __restrict__ feats) {
  __shared__ float red[256];
  int g = blockIdx.x;
  int tid = threadIdx.x;
  int c = tid & 127;
  int h = tid >> 7;
  float acc = 0.f;
  int a = ustart[g], b = ustart[g+1];
  for (int r = a + h; r < b; r += 2) acc += xu[(size_t)r*FD + c];
  a = istart[g]; b = istart[g+1];
  for (int r = a + h; r < b; r += 2) acc += xi[(size_t)r*FD + c];
  red[tid] = acc;
  __syncthreads();
  if (tid < 128) {
    float tot = red[tid] + red[tid+128];
    feats[(size_t)g*FD + c] = tot * invcnt[g];
  }
}

__global__ __launch_bounds__(256) void k_heads(const float* __restrict__ feats,
                                               const float* __restrict__ fcW,
                                               const float* __restrict__ fcb,
                                               float* __restrict__ logits) {
  int idx = blockIdx.x*256 + threadIdx.x;
  if (idx >= LOGITS_N) return;
  int l = idx >> 13;
  int rem = idx & 8191;
  int g = rem >> 4;
  int c = rem & 15;
  const float* f = feats + ((size_t)l*NG + g)*FD;
  const float* w = fcW + ((size_t)l*NC + c)*FD;
  float s = 0.f;
  #pragma unroll
  for (int k = 0; k < FD; k += 4) {
    float4 fv = *(const float4*)(f + k);
    float4 wv = *(const float4*)(w + k);
    s += fv.x*wv.x + fv.y*wv.y + fv.z*wv.z + fv.w*wv.w;
  }
  logits[idx] = s + fcb[l*NC + c];
}

extern "C" void kernel_launch(void* const* d_in, const int* in_sizes, int n_in,
                              void* d_out, int out_size, void* d_ws, size_t ws_size,
                              hipStream_t stream) {
  const float* x_user   = (const float*)d_in[0];
  const float* x_item   = (const float*)d_in[1];
  const int*   eu2i     = (const int*)d_in[2];
  const int*   ei2u     = (const int*)d_in[3];
  const int*   bu       = (const int*)d_in[4];
  const int*   bi       = (const int*)d_in[5];
  const float* Wrel_u2i = (const float*)d_in[6];
  const float* Wroot_u2i= (const float*)d_in[7];
  const float* b_u2i    = (const float*)d_in[8];
  const float* Wrel_i2u = (const float*)d_in[9];
  const float* Wroot_i2u= (const float*)d_in[10];
  const float* b_i2u    = (const float*)d_in[11];
  const float* bn_g_user= (const float*)d_in[12];
  const float* bn_b_user= (const float*)d_in[13];
  const float* bn_g_item= (const float*)d_in[14];
  const float* bn_b_item= (const float*)d_in[15];
  const float* fcW      = (const float*)d_in[16];
  const float* fcb      = (const float*)d_in[17];

  char* ws = (char*)d_ws;
  int*   deg    = (int*)(ws + OFF_DEG);
  int*   gcnt   = (int*)(ws + OFF_GCNT);
  int*   rowptr = (int*)(ws + OFF_ROWPTR);
  int*   cursor = (int*)(ws + OFF_CURSOR);
  int*   ustart = (int*)(ws + OFF_USTART);
  int*   istart = (int*)(ws + OFF_ISTART);
  float* invcnt = (float*)(ws + OFF_INVCNT);
  float* psum   = (float*)(ws + OFF_BNPART);
  float* psq    = psum + 2*196*128;
  float* bnsc   = (float*)(ws + OFF_BNSC);
  float* bnsh   = (float*)(ws + OFF_BNSH);
  float* WT     = (float*)(ws + OFF_WT);
  int*   csr    = (int*)(ws + OFF_CSR);
  float* aggI   = (float*)(ws + OFF_AGGI);
  float* aggU   = (float*)(ws + OFF_AGGU);
  float* xu     = (float*)(ws + OFF_XU);
  float* xi     = (float*)(ws + OFF_XI);
  float* fout   = (float*)d_out;
  float* featsAll = fout + LOGITS_N;

  hipMemsetAsync(ws + OFF_DEG, 0, MEMSET_BYTES, stream);
  k_hist_edges<<<6250, 256, 0, stream>>>(eu2i, ei2u, deg);
  k_hist_batch<<<391, 256, 0, stream>>>(bu, bi, gcnt);
  k_scan_big<<<1, 1024, 0, stream>>>(deg, rowptr, cursor);
  k_scan_g<<<1, 512, 0, stream>>>(gcnt, ustart, istart, invcnt);
  k_fill_csr<<<6250, 256, 0, stream>>>(eu2i, ei2u, cursor, csr);
  k_transposeW<<<768, 256, 0, stream>>>(Wrel_u2i, Wroot_u2i, Wrel_i2u, Wroot_i2u, WT);

  const float* curU = x_user;
  const float* curI = x_item;
  for (int l = 0; l < NL; l++) {
    k_gather<<<12500, 256, 0, stream>>>(curU, rowptr, csr, aggI, 0);
    k_gather<<<12500, 256, 0, stream>>>(curI, rowptr, csr, aggU, NN);
    k_gemm<<<391, 256, 0, stream>>>(aggI, curI, WT + (l*2+0)*32768, b_u2i + l*FD, aggI);
    k_gemm<<<391, 256, 0, stream>>>(aggU, curU, WT + (l*2+1)*32768, b_i2u + l*FD, aggU);
    k_stats<<<dim3(196,2), 128, 0, stream>>>(aggU, aggI, psum, psq);
    k_bnfinal<<<1, 256, 0, stream>>>(psum, psq, bn_g_user, bn_b_user,
                                     bn_g_item, bn_b_item, bnsc, bnsh);
    k_bnapply<<<dim3(391,2), 256, 0, stream>>>(aggU, aggI, bnsc, bnsh, xu, xi);
    k_pool<<<NG, 256, 0, stream>>>(xu, xi, ustart, istart, invcnt,
                                   featsAll + (size_t)l*NG*FD);
    curU = xu; curI = xi;
  }
  k_heads<<<96, 256, 0, stream>>>(featsAll, fcW, fcb, fout);
}

// Round 2
// 1150.982 us; speedup vs baseline: 1.5150x; 1.5150x over previous
//
#include <hip/hip_runtime.h>

#define NN 50000
#define FD 128
#define NE 800000
#define NG 512
#define NC 16
#define NL 3
#define NTOT 100000
#define NBLK 391            // ceil(100000/256) and ceil(50000/128)
#define BNEPS 1e-5f
#define LOGITS_N (NL*NG*NC)

// ---- workspace layout (bytes), offsets 512-aligned ----
#define OFF_DEG      0ul          // 100000 int
#define OFF_GCNT     400384ul     // 2*512 int
#define MEMSET_BYTES 404480ul     // covers DEG + GCNT
#define OFF_ROWPTR   409600ul     // 100001 int
#define OFF_CURSOR   819200ul     // 100000 int
#define OFF_BSUM     1219584ul    // 512 int
#define OFF_USTART   1222144ul    // 513 int
#define OFF_ISTART   1224704ul    // 513 int
#define OFF_INVCNT   1227264ul    // 512 f32
#define OFF_BNSC     1229312ul    // 256 f32
#define OFF_BNSH     1230336ul    // 256 f32
#define OFF_BNPART   1231360ul    // 2 * (2*391*128) f32  (psum, psq)
#define OFF_WT       2032640ul    // 6*256*128 f32
#define OFF_CSR      2819072ul    // 1600000 int
#define OFF_AGGI     9219072ul    // 50000*128 f32 (in-place -> new_i)
#define OFF_AGGU     34819072ul   // 50000*128 f32 (in-place -> new_u)
#define OFF_XU       60419072ul   // 50000*128 f32
#define OFF_XI       86019072ul   // 50000*128 f32

__global__ __launch_bounds__(256) void k_hist_edges(const int* __restrict__ eu2i,
                                                    const int* __restrict__ ei2u,
                                                    int* __restrict__ deg) {
  int idx = blockIdx.x*256 + threadIdx.x;
  if (idx >= 2*NE) return;
  int rel = idx >= NE;
  int e = rel ? idx - NE : idx;
  const int* edge = rel ? ei2u : eu2i;
  int dst = edge[NE + e];
  atomicAdd(&deg[rel ? NN + dst : dst], 1);
}

__global__ __launch_bounds__(256) void k_hist_batch(const int* __restrict__ bu,
                                                    const int* __restrict__ bi,
                                                    int* __restrict__ gcnt) {
  int i = blockIdx.x*256 + threadIdx.x;
  if (i >= NTOT) return;
  int type = i >= NN;
  int g = type ? bi[i-NN] : bu[i];
  atomicAdd(&gcnt[type*NG + g], 1);
}

// ---- parallel scan of deg[100000] -> rowptr/cursor (3 kernels) ----
__global__ __launch_bounds__(256) void k_blocksum(const int* __restrict__ deg,
                                                  int* __restrict__ bsum) {
  int t = threadIdx.x;
  int idx = blockIdx.x*256 + t;
  int v = (idx < NTOT) ? deg[idx] : 0;
  __shared__ int red[4];
  #pragma unroll
  for (int o = 32; o; o >>= 1) v += __shfl_down(v, o);
  if ((t & 63) == 0) red[t >> 6] = v;
  __syncthreads();
  if (t == 0) bsum[blockIdx.x] = red[0] + red[1] + red[2] + red[3];
}

__global__ __launch_bounds__(512) void k_scanbsum(int* __restrict__ bsum) {
  __shared__ int s[512];
  int t = threadIdx.x;
  int v = (t < NBLK) ? bsum[t] : 0;
  s[t] = v;
  __syncthreads();
  for (int o = 1; o < 512; o <<= 1) {
    int u = (t >= o) ? s[t-o] : 0;
    __syncthreads();
    s[t] += u;
    __syncthreads();
  }
  if (t < NBLK) bsum[t] = s[t] - v;   // exclusive
}

__global__ __launch_bounds__(256) void k_writerowptr(const int* __restrict__ deg,
                                                     const int* __restrict__ bsum,
                                                     int* __restrict__ rowptr,
                                                     int* __restrict__ cursor) {
  __shared__ int s[256];
  int t = threadIdx.x;
  int idx = blockIdx.x*256 + t;
  int v = (idx < NTOT) ? deg[idx] : 0;
  s[t] = v;
  __syncthreads();
  for (int o = 1; o < 256; o <<= 1) {
    int u = (t >= o) ? s[t-o] : 0;
    __syncthreads();
    s[t] += u;
    __syncthreads();
  }
  int excl = s[t] - v + bsum[blockIdx.x];
  if (idx < NTOT) { rowptr[idx] = excl; cursor[idx] = excl; }
  if (idx == NTOT-1) rowptr[NTOT] = excl + v;
}

__global__ __launch_bounds__(512) void k_scan_g(const int* __restrict__ gcnt,
                                                int* __restrict__ ustart,
                                                int* __restrict__ istart,
                                                float* __restrict__ invcnt) {
  __shared__ int pu[512], pi[512];
  int t = threadIdx.x;
  int cu = gcnt[t], ci = gcnt[NG + t];
  pu[t] = cu; pi[t] = ci;
  __syncthreads();
  for (int off = 1; off < 512; off <<= 1) {
    int vu = (t >= off) ? pu[t-off] : 0;
    int vi = (t >= off) ? pi[t-off] : 0;
    __syncthreads();
    pu[t] += vu; pi[t] += vi;
    __syncthreads();
  }
  ustart[t] = pu[t] - cu;
  istart[t] = pi[t] - ci;
  if (t == 511) { ustart[NG] = pu[511]; istart[NG] = pi[511]; }
  int c = cu + ci;
  invcnt[t] = 1.0f / (float)(c > 0 ? c : 1);
}

__global__ __launch_bounds__(256) void k_fill_csr(const int* __restrict__ eu2i,
                                                  const int* __restrict__ ei2u,
                                                  int* __restrict__ cursor,
                                                  int* __restrict__ csr) {
  int idx = blockIdx.x*256 + threadIdx.x;
  if (idx >= 2*NE) return;
  int rel = idx >= NE;
  int e = rel ? idx - NE : idx;
  const int* edge = rel ? ei2u : eu2i;
  int src = edge[e];
  int dst = edge[NE + e];
  int pos = atomicAdd(&cursor[rel ? NN + dst : dst], 1);
  csr[pos] = src;
}

// WT[lr][k][h]: lr = l*2+rel (rel0=u2i, rel1=i2u); k<128 -> Wrel[l][h][k], else Wroot
__global__ __launch_bounds__(256) void k_transposeW(
    const float* __restrict__ WrelA, const float* __restrict__ WrootA,
    const float* __restrict__ WrelB, const float* __restrict__ WrootB,
    float* __restrict__ WT) {
  int idx = blockIdx.x*256 + threadIdx.x;   // < 6*32768
  int lr = idx >> 15;
  int rem = idx & 32767;
  int k = rem >> 7;
  int h = rem & 127;
  int l = lr >> 1;
  int rel = lr & 1;
  const float* Wr = rel ? WrelB : WrelA;
  const float* Wo = rel ? WrootB : WrootA;
  float v = (k < FD) ? Wr[(l*FD + h)*FD + k] : Wo[(l*FD + h)*FD + (k-FD)];
  WT[idx] = v;
}

// one wave per destination row; 4 independent chains; wave-uniform row so
// CSR index loads become s_load (scalar pipe) and row-load base is SGPR.
// blocks [0,12500): u2i (src curU -> aggI), [12500,25000): i2u (curI -> aggU)
__global__ __launch_bounds__(256) void k_gather(const float* __restrict__ curU,
                                                const float* __restrict__ curI,
                                                const int* __restrict__ rowptr,
                                                const int* __restrict__ csr,
                                                float* __restrict__ aggI,
                                                float* __restrict__ aggU) {
  int b = blockIdx.x;
  int half = b >= 12500;
  int rb = half ? b - 12500 : b;
  const float* src = half ? curI : curU;
  float* out = half ? aggU : aggI;
  int slotbase = half ? NN : 0;
  int wid = __builtin_amdgcn_readfirstlane(threadIdx.x >> 6);
  int row = rb*4 + wid;
  int lane = threadIdx.x & 63;
  int off = lane*2;
  const int* rp = rowptr + slotbase + row;
  int p = rp[0];
  int pe = rp[1];
  float2 a0 = make_float2(0.f,0.f), a1 = make_float2(0.f,0.f);
  float2 a2 = make_float2(0.f,0.f), a3 = make_float2(0.f,0.f);
  for (; p+4 <= pe; p += 4) {
    int s0 = csr[p], s1 = csr[p+1], s2 = csr[p+2], s3 = csr[p+3];
    float2 v0 = *(const float2*)(src + (size_t)s0*FD + off);
    float2 v1 = *(const float2*)(src + (size_t)s1*FD + off);
    float2 v2 = *(const float2*)(src + (size_t)s2*FD + off);
    float2 v3 = *(const float2*)(src + (size_t)s3*FD + off);
    a0.x += v0.x; a0.y += v0.y;
    a1.x += v1.x; a1.y += v1.y;
    a2.x += v2.x; a2.y += v2.y;
    a3.x += v3.x; a3.y += v3.y;
  }
  for (; p < pe; p++) {
    int s0 = csr[p];
    float2 v0 = *(const float2*)(src + (size_t)s0*FD + off);
    a0.x += v0.x; a0.y += v0.y;
  }
  a0.x += (a1.x + a2.x) + a3.x;
  a0.y += (a1.y + a2.y) + a3.y;
  *(float2*)(out + (size_t)row*FD + off) = a0;
}

// new[n,h] = A1@WT[0:128] + A2@WT[128:256] + bias; BN relu-stats fused in epilogue.
// ty (blockIdx.y): 0=user update (i2u weights), 1=item update (u2i weights).
// out == A1 is safe: a block only reads/writes its own 128 rows, barrier-separated.
__global__ __launch_bounds__(256) void k_gemm(float* __restrict__ aggU,
                                              float* __restrict__ aggI,
                                              const float* __restrict__ curU,
                                              const float* __restrict__ curI,
                                              const float* __restrict__ WTl,
                                              const float* __restrict__ bI2U,
                                              const float* __restrict__ bU2I,
                                              float* __restrict__ psum,
                                              float* __restrict__ psq) {
  __shared__ float As[16][128];
  __shared__ float Bs[16][128];
  int ty = blockIdx.y;
  float* A1 = ty ? aggI : aggU;
  const float* A2 = ty ? curI : curU;
  const float* WTp = ty ? WTl : (WTl + 32768);
  const float* bias = ty ? bU2I : bI2U;
  int tid = threadIdx.x;
  int n0 = blockIdx.x * 128;
  int tn = (tid & 15) * 8;
  int th = (tid >> 4) * 8;
  float acc[8][8];
  #pragma unroll
  for (int i=0;i<8;i++)
    #pragma unroll
    for (int j=0;j<8;j++) acc[i][j] = 0.f;

  for (int k0 = 0; k0 < 256; k0 += 16) {
    const float* Asrc = (k0 < FD) ? (A1 + k0) : (A2 + (k0 - FD));
    #pragma unroll
    for (int i = 0; i < 2; i++) {
      int idx = tid + i*256;
      int row = idx >> 2;
      int kq = (idx & 3) * 4;
      float4 v = make_float4(0.f,0.f,0.f,0.f);
      int r = n0 + row;
      if (r < NN) v = *(const float4*)(Asrc + (size_t)r*FD + kq);
      As[kq+0][row] = v.x; As[kq+1][row] = v.y; As[kq+2][row] = v.z; As[kq+3][row] = v.w;
    }
    #pragma unroll
    for (int i = 0; i < 2; i++) {
      int idx = tid + i*256;
      int kk = idx >> 5;
      int h4 = (idx & 31) * 4;
      *(float4*)&Bs[kk][h4] = *(const float4*)(WTp + (size_t)(k0+kk)*FD + h4);
    }
    __syncthreads();
    #pragma unroll
    for (int k = 0; k < 16; k++) {
      float a[8], bb[8];
      *(float4*)&a[0] = *(const float4*)&As[k][tn];
      *(float4*)&a[4] = *(const float4*)&As[k][tn+4];
      *(float4*)&bb[0] = *(const float4*)&Bs[k][th];
      *(float4*)&bb[4] = *(const float4*)&Bs[k][th+4];
      #pragma unroll
      for (int i=0;i<8;i++)
        #pragma unroll
        for (int j=0;j<8;j++)
          acc[i][j] = fmaf(a[i], bb[j], acc[i][j]);
    }
    __syncthreads();
  }
  float bj[8];
  #pragma unroll
  for (int j=0;j<8;j++) bj[j] = bias[th+j];
  float sv[8], qv[8];
  #pragma unroll
  for (int j=0;j<8;j++) { sv[j]=0.f; qv[j]=0.f; }
  #pragma unroll
  for (int i=0;i<8;i++) {
    int r = n0 + tn + i;
    bool ok = r < NN;
    #pragma unroll
    for (int j=0;j<8;j++) {
      float v = acc[i][j] + bj[j];
      acc[i][j] = v;
      float y = (ok && v > 0.f) ? v : 0.f;
      sv[j] += y; qv[j] += y*y;
    }
    if (ok) {
      *(float4*)(A1 + (size_t)r*FD + th) = *(float4*)&acc[i][0];
      *(float4*)(A1 + (size_t)r*FD + th + 4) = *(float4*)&acc[i][4];
    }
  }
  // reduce stats across the 16 lanes sharing this column group (lanes differ in tid&15)
  #pragma unroll
  for (int o = 1; o < 16; o <<= 1) {
    #pragma unroll
    for (int j=0;j<8;j++) {
      sv[j] += __shfl_xor(sv[j], o);
      qv[j] += __shfl_xor(qv[j], o);
    }
  }
  if ((tid & 15) == 0) {
    // stat slot: 0=user, 1=item  (== ty mapping: ty0 writes new_u)
    int o = ((ty ? NBLK : 0) + blockIdx.x)*FD + th;
    // ty0 = user -> slot 0; ty1 = item -> slot NBLK.. wait: slot base = ty*NBLK
    o = (ty*NBLK + blockIdx.x)*FD + th;
    #pragma unroll
    for (int j=0;j<8;j++) { psum[o+j] = sv[j]; psq[o+j] = qv[j]; }
  }
}

__global__ __launch_bounds__(256) void k_bnfinal(const float* __restrict__ psum,
                                                 const float* __restrict__ psq,
                                                 const float* __restrict__ gu,
                                                 const float* __restrict__ bu,
                                                 const float* __restrict__ gi,
                                                 const float* __restrict__ bi,
                                                 float* __restrict__ bnsc,
                                                 float* __restrict__ bnsh) {
  int tid = threadIdx.x;
  int type = tid >> 7;            // 0=user, 1=item
  int c = tid & 127;
  int base = type*NBLK*FD + c;
  float s0=0.f,s1=0.f,s2p=0.f,s3=0.f,q0=0.f,q1=0.f,q2=0.f,q3=0.f;
  int b = 0;
  for (; b+4 <= NBLK; b += 4) {
    s0 += psum[base + (b+0)*FD]; q0 += psq[base + (b+0)*FD];
    s1 += psum[base + (b+1)*FD]; q1 += psq[base + (b+1)*FD];
    s2p += psum[base + (b+2)*FD]; q2 += psq[base + (b+2)*FD];
    s3 += psum[base + (b+3)*FD]; q3 += psq[base + (b+3)*FD];
  }
  for (; b < NBLK; b++) { s0 += psum[base + b*FD]; q0 += psq[base + b*FD]; }
  float s = (s0+s1)+(s2p+s3);
  float q = (q0+q1)+(q2+q3);
  float inv = 1.0f / (float)NN;
  float mean = s * inv;
  float var = q * inv - mean*mean;
  float rstd = rsqrtf(var + BNEPS);
  float g = type ? gi[c] : gu[c];
  float bb = type ? bi[c] : bu[c];
  float sc = rstd * g;
  bnsc[tid] = sc;
  bnsh[tid] = bb - mean * sc;
}

// BN-apply + fused mean-pool: batch ids (bu/bi) ARE per-row graph ids, sorted ->
// accumulate per-graph runs in registers, one atomicAdd per run per column.
__global__ __launch_bounds__(256) void k_bnapply(const float* __restrict__ newU,
                                                 const float* __restrict__ newI,
                                                 const int* __restrict__ bu,
                                                 const int* __restrict__ bi,
                                                 const float* __restrict__ bnsc,
                                                 const float* __restrict__ bnsh,
                                                 const float* __restrict__ invcnt,
                                                 float* __restrict__ xu,
                                                 float* __restrict__ xi,
                                                 float* __restrict__ feats) {
  int type = blockIdx.y;          // 0=user, 1=item
  const float* in = type ? newI : newU;
  const int* bt = type ? bi : bu;
  float* out = type ? xi : xu;
  int tid = threadIdx.x;
  int c = tid & 127;
  int rh = tid >> 7;
  float sc = bnsc[type*128 + c];
  float sh = bnsh[type*128 + c];
  int rs = blockIdx.x*128 + rh*64;
  int re = rs + 64; if (re > NN) re = NN;
  if (rs >= re) return;
  int gcur = bt[rs];
  float acc = 0.f;
  for (int r = rs; r < re; r++) {
    int g = bt[r];
    if (g != gcur) {
      atomicAdd(&feats[(size_t)gcur*FD + c], acc * invcnt[gcur]);
      acc = 0.f; gcur = g;
    }
    float y = in[(size_t)r*FD + c];
    y = y > 0.f ? y : 0.f;
    float o = y * sc + sh;
    out[(size_t)r*FD + c] = o;
    acc += o;
  }
  atomicAdd(&feats[(size_t)gcur*FD + c], acc * invcnt[gcur]);
}

__global__ __launch_bounds__(256) void k_heads(const float* __restrict__ feats,
                                               const float* __restrict__ fcW,
                                               const float* __restrict__ fcb,
                                               float* __restrict__ logits) {
  int idx = blockIdx.x*256 + threadIdx.x;
  if (idx >= LOGITS_N) return;
  int l = idx >> 13;
  int rem = idx & 8191;
  int g = rem >> 4;
  int c = rem & 15;
  const float* f = feats + ((size_t)l*NG + g)*FD;
  const float* w = fcW + ((size_t)l*NC + c)*FD;
  float s = 0.f;
  #pragma unroll
  for (int k = 0; k < FD; k += 4) {
    float4 fv = *(const float4*)(f + k);
    float4 wv = *(const float4*)(w + k);
    s += fv.x*wv.x + fv.y*wv.y + fv.z*wv.z + fv.w*wv.w;
  }
  logits[idx] = s + fcb[l*NC + c];
}

extern "C" void kernel_launch(void* const* d_in, const int* in_sizes, int n_in,
                              void* d_out, int out_size, void* d_ws, size_t ws_size,
                              hipStream_t stream) {
  const float* x_user   = (const float*)d_in[0];
  const float* x_item   = (const float*)d_in[1];
  const int*   eu2i     = (const int*)d_in[2];
  const int*   ei2u     = (const int*)d_in[3];
  const int*   bu       = (const int*)d_in[4];
  const int*   bi       = (const int*)d_in[5];
  const float* Wrel_u2i = (const float*)d_in[6];
  const float* Wroot_u2i= (const float*)d_in[7];
  const float* b_u2i    = (const float*)d_in[8];
  const float* Wrel_i2u = (const float*)d_in[9];
  const float* Wroot_i2u= (const float*)d_in[10];
  const float* b_i2u    = (const float*)d_in[11];
  const float* bn_g_user= (const float*)d_in[12];
  const float* bn_b_user= (const float*)d_in[13];
  const float* bn_g_item= (const float*)d_in[14];
  const float* bn_b_item= (const float*)d_in[15];
  const float* fcW      = (const float*)d_in[16];
  const float* fcb      = (const float*)d_in[17];

  char* ws = (char*)d_ws;
  int*   deg    = (int*)(ws + OFF_DEG);
  int*   gcnt   = (int*)(ws + OFF_GCNT);
  int*   rowptr = (int*)(ws + OFF_ROWPTR);
  int*   cursor = (int*)(ws + OFF_CURSOR);
  int*   bsum   = (int*)(ws + OFF_BSUM);
  int*   ustart = (int*)(ws + OFF_USTART);
  int*   istart = (int*)(ws + OFF_ISTART);
  float* invcnt = (float*)(ws + OFF_INVCNT);
  float* bnsc   = (float*)(ws + OFF_BNSC);
  float* bnsh   = (float*)(ws + OFF_BNSH);
  float* psum   = (float*)(ws + OFF_BNPART);
  float* psq    = psum + 2*NBLK*FD;
  float* WT     = (float*)(ws + OFF_WT);
  int*   csr    = (int*)(ws + OFF_CSR);
  float* aggI   = (float*)(ws + OFF_AGGI);
  float* aggU   = (float*)(ws + OFF_AGGU);
  float* xu     = (float*)(ws + OFF_XU);
  float* xi     = (float*)(ws + OFF_XI);
  float* fout   = (float*)d_out;
  float* featsAll = fout + LOGITS_N;

  hipMemsetAsync(ws + OFF_DEG, 0, MEMSET_BYTES, stream);
  hipMemsetAsync(featsAll, 0, (size_t)NL*NG*FD*sizeof(float), stream);
  k_hist_edges<<<6250, 256, 0, stream>>>(eu2i, ei2u, deg);
  k_hist_batch<<<391, 256, 0, stream>>>(bu, bi, gcnt);
  k_blocksum<<<NBLK, 256, 0, stream>>>(deg, bsum);
  k_scanbsum<<<1, 512, 0, stream>>>(bsum);
  k_writerowptr<<<NBLK, 256, 0, stream>>>(deg, bsum, rowptr, cursor);
  k_scan_g<<<1, 512, 0, stream>>>(gcnt, ustart, istart, invcnt);
  k_fill_csr<<<6250, 256, 0, stream>>>(eu2i, ei2u, cursor, csr);
  k_transposeW<<<768, 256, 0, stream>>>(Wrel_u2i, Wroot_u2i, Wrel_i2u, Wroot_i2u, WT);

  const float* curU = x_user;
  const float* curI = x_item;
  for (int l = 0; l < NL; l++) {
    k_gather<<<25000, 256, 0, stream>>>(curU, curI, rowptr, csr, aggI, aggU);
    k_gemm<<<dim3(NBLK,2), 256, 0, stream>>>(aggU, aggI, curU, curI,
                                             WT + (size_t)l*2*32768,
                                             b_i2u + l*FD, b_u2i + l*FD,
                                             psum, psq);
    k_bnfinal<<<1, 256, 0, stream>>>(psum, psq, bn_g_user, bn_b_user,
                                     bn_g_item, bn_b_item, bnsc, bnsh);
    k_bnapply<<<dim3(NBLK,2), 256, 0, stream>>>(aggU, aggI, bu, bi, bnsc, bnsh,
                                                invcnt, xu, xi,
                                                featsAll + (size_t)l*NG*FD);
    curU = xu; curI = xi;
  }
  k_heads<<<96, 256, 0, stream>>>(featsAll, fcW, fcb, fout);
}

// Round 3
// 790.458 us; speedup vs baseline: 2.2061x; 1.4561x over previous
//
#include <hip/hip_runtime.h>

#define NN 50000
#define FD 128
#define NE 800000
#define NG 512
#define NC 16
#define NL 3
#define NTOT 100000
#define NBLK 391            // ceil(100000/256) and ceil(50000/128)
#define BNEPS 1e-5f
#define LOGITS_N (NL*NG*NC)

typedef unsigned short u16;
typedef __attribute__((ext_vector_type(8))) short short8;
typedef __attribute__((ext_vector_type(4))) float f32x4;

// ---- workspace layout (bytes), offsets 512-aligned ----
#define OFF_DEG      0ul          // 100000 int
#define OFF_GCNT     400384ul     // 2*512 int
#define MEMSET_BYTES 404480ul     // covers DEG + GCNT
#define OFF_ROWPTR   409600ul     // 100001 int
#define OFF_CURSOR   819200ul     // 100000 int
#define OFF_BSUM     1219584ul    // 512 int
#define OFF_INVCNT   1222144ul    // 512 f32
#define OFF_BNSC     1224704ul    // 256 f32
#define OFF_BNSH     1225728ul    // 256 f32
#define OFF_BNPART   1226752ul    // 2*(2*391*128) f32 (psum, psq)
#define OFF_WB       2027520ul    // 6*128*256 bf16
#define OFF_CSR      2420736ul    // 1600000 int
#define OFF_AGGI     8820736ul    // 50000*128 bf16 (in-place -> new_i)
#define OFF_AGGU     21620736ul   // 50000*128 bf16 (in-place -> new_u)
#define OFF_XU       34420736ul   // 50000*128 bf16
#define OFF_XI       47220736ul   // 50000*128 bf16
#define OFF_XU0      60020736ul   // 50000*128 bf16 (initial cast)
#define OFF_XI0      72820736ul   // 50000*128 bf16

static __device__ __forceinline__ float bf2f(u16 v) {
  return __uint_as_float(((unsigned)v) << 16);
}
static __device__ __forceinline__ u16 f2bf(float f) {
  unsigned u = __float_as_uint(f);
  return (u16)((u + 0x7FFFu + ((u >> 16) & 1u)) >> 16);
}

__global__ __launch_bounds__(256) void k_hist_edges(const int* __restrict__ eu2i,
                                                    const int* __restrict__ ei2u,
                                                    int* __restrict__ deg) {
  int idx = blockIdx.x*256 + threadIdx.x;
  if (idx >= 2*NE) return;
  int rel = idx >= NE;
  int e = rel ? idx - NE : idx;
  const int* edge = rel ? ei2u : eu2i;
  int dst = edge[NE + e];
  atomicAdd(&deg[rel ? NN + dst : dst], 1);
}

__global__ __launch_bounds__(256) void k_hist_batch(const int* __restrict__ bu,
                                                    const int* __restrict__ bi,
                                                    int* __restrict__ gcnt) {
  int i = blockIdx.x*256 + threadIdx.x;
  if (i >= NTOT) return;
  int type = i >= NN;
  int g = type ? bi[i-NN] : bu[i];
  atomicAdd(&gcnt[type*NG + g], 1);
}

// ---- parallel scan of deg[100000] -> rowptr/cursor ----
__global__ __launch_bounds__(256) void k_blocksum(const int* __restrict__ deg,
                                                  int* __restrict__ bsum) {
  int t = threadIdx.x;
  int idx = blockIdx.x*256 + t;
  int v = (idx < NTOT) ? deg[idx] : 0;
  __shared__ int red[4];
  #pragma unroll
  for (int o = 32; o; o >>= 1) v += __shfl_down(v, o);
  if ((t & 63) == 0) red[t >> 6] = v;
  __syncthreads();
  if (t == 0) bsum[blockIdx.x] = red[0] + red[1] + red[2] + red[3];
}

__global__ __launch_bounds__(512) void k_scanbsum(int* __restrict__ bsum) {
  __shared__ int s[512];
  int t = threadIdx.x;
  int v = (t < NBLK) ? bsum[t] : 0;
  s[t] = v;
  __syncthreads();
  for (int o = 1; o < 512; o <<= 1) {
    int u = (t >= o) ? s[t-o] : 0;
    __syncthreads();
    s[t] += u;
    __syncthreads();
  }
  if (t < NBLK) bsum[t] = s[t] - v;   // exclusive
}

__global__ __launch_bounds__(256) void k_writerowptr(const int* __restrict__ deg,
                                                     const int* __restrict__ bsum,
                                                     int* __restrict__ rowptr,
                                                     int* __restrict__ cursor) {
  __shared__ int s[256];
  int t = threadIdx.x;
  int idx = blockIdx.x*256 + t;
  int v = (idx < NTOT) ? deg[idx] : 0;
  s[t] = v;
  __syncthreads();
  for (int o = 1; o < 256; o <<= 1) {
    int u = (t >= o) ? s[t-o] : 0;
    __syncthreads();
    s[t] += u;
    __syncthreads();
  }
  int excl = s[t] - v + bsum[blockIdx.x];
  if (idx < NTOT) { rowptr[idx] = excl; cursor[idx] = excl; }
  if (idx == NTOT-1) rowptr[NTOT] = excl + v;
}

__global__ __launch_bounds__(512) void k_invcnt(const int* __restrict__ gcnt,
                                                float* __restrict__ invcnt) {
  int t = threadIdx.x;
  int c = gcnt[t] + gcnt[NG + t];
  invcnt[t] = 1.0f / (float)(c > 0 ? c : 1);
}

__global__ __launch_bounds__(256) void k_fill_csr(const int* __restrict__ eu2i,
                                                  const int* __restrict__ ei2u,
                                                  int* __restrict__ cursor,
                                                  int* __restrict__ csr) {
  int idx = blockIdx.x*256 + threadIdx.x;
  if (idx >= 2*NE) return;
  int rel = idx >= NE;
  int e = rel ? idx - NE : idx;
  const int* edge = rel ? ei2u : eu2i;
  int src = edge[e];
  int dst = edge[NE + e];
  int pos = atomicAdd(&cursor[rel ? NN + dst : dst], 1);
  csr[pos] = src;
}

// fp32 -> bf16 cast of initial features
__global__ __launch_bounds__(256) void k_castX(const float* __restrict__ xu,
                                               const float* __restrict__ xi,
                                               u16* __restrict__ xbu,
                                               u16* __restrict__ xbi) {
  int b = blockIdx.x;
  int half = b >= 6250;
  const float* src = half ? xi : xu;
  u16* dst = half ? xbi : xbu;
  int i = ((half ? b - 6250 : b)*256 + threadIdx.x) * 4;
  float4 v = *(const float4*)(src + i);
  ushort4 o = { f2bf(v.x), f2bf(v.y), f2bf(v.z), f2bf(v.w) };
  *(ushort4*)(dst + i) = o;
}

// WB[lr][h][k]: k<128 -> Wrel[l][h][k], else Wroot[l][h][k-128]   (bf16)
__global__ __launch_bounds__(256) void k_castW(const float* __restrict__ WrelA,
                                               const float* __restrict__ WrootA,
                                               const float* __restrict__ WrelB,
                                               const float* __restrict__ WrootB,
                                               u16* __restrict__ WB) {
  int idx = blockIdx.x*256 + threadIdx.x;   // < 6*32768
  int lr = idx >> 15;
  int rem = idx & 32767;
  int h = rem >> 8;
  int k = rem & 255;
  int l = lr >> 1;
  int rel = lr & 1;
  const float* Wr = rel ? WrelB : WrelA;
  const float* Wo = rel ? WrootB : WrootA;
  float v = (k < FD) ? Wr[(l*FD + h)*FD + k] : Wo[(l*FD + h)*FD + (k-FD)];
  WB[idx] = f2bf(v);
}

// one wave per destination row; each 8B load covers half of TWO source rows
// (half-waves take different sources of a pair); 4 independent chains.
// blocks [0,12500): u2i (curU -> aggI), [12500,25000): i2u (curI -> aggU)
__global__ __launch_bounds__(256) void k_gather(const u16* __restrict__ curU,
                                                const u16* __restrict__ curI,
                                                const int* __restrict__ rowptr,
                                                const int* __restrict__ csr,
                                                u16* __restrict__ aggI,
                                                u16* __restrict__ aggU) {
  int b = blockIdx.x;
  int half = b >= 12500;
  int rb = half ? b - 12500 : b;
  const u16* src = half ? curI : curU;
  u16* out = half ? aggU : aggI;
  int slotbase = half ? NN : 0;
  int wid = __builtin_amdgcn_readfirstlane(threadIdx.x >> 6);
  int row = rb*4 + wid;
  int lane = threadIdx.x & 63;
  int hw = lane >> 5;            // which source of the pair
  int off = (lane & 31) * 4;     // 4 bf16 elements per lane
  const int* rp = rowptr + slotbase + row;
  int p = rp[0];
  int pe = rp[1];
  float4 a0 = {0,0,0,0}, a1 = {0,0,0,0}, a2 = {0,0,0,0}, a3 = {0,0,0,0};
  for (; p + 8 <= pe; p += 8) {
    int s0 = csr[p + 0 + hw];
    int s1 = csr[p + 2 + hw];
    int s2 = csr[p + 4 + hw];
    int s3 = csr[p + 6 + hw];
    ushort4 v0 = *(const ushort4*)(src + (size_t)s0*FD + off);
    ushort4 v1 = *(const ushort4*)(src + (size_t)s1*FD + off);
    ushort4 v2 = *(const ushort4*)(src + (size_t)s2*FD + off);
    ushort4 v3 = *(const ushort4*)(src + (size_t)s3*FD + off);
    a0.x += bf2f(v0.x); a0.y += bf2f(v0.y); a0.z += bf2f(v0.z); a0.w += bf2f(v0.w);
    a1.x += bf2f(v1.x); a1.y += bf2f(v1.y); a1.z += bf2f(v1.z); a1.w += bf2f(v1.w);
    a2.x += bf2f(v2.x); a2.y += bf2f(v2.y); a2.z += bf2f(v2.z); a2.w += bf2f(v2.w);
    a3.x += bf2f(v3.x); a3.y += bf2f(v3.y); a3.z += bf2f(v3.z); a3.w += bf2f(v3.w);
  }
  for (; p + 2 <= pe; p += 2) {
    int s0 = csr[p + hw];
    ushort4 v0 = *(const ushort4*)(src + (size_t)s0*FD + off);
    a0.x += bf2f(v0.x); a0.y += bf2f(v0.y); a0.z += bf2f(v0.z); a0.w += bf2f(v0.w);
  }
  if (p < pe && hw == 0) {       // odd tail: only half-wave 0 contributes
    int s0 = csr[p];
    ushort4 v0 = *(const ushort4*)(src + (size_t)s0*FD + off);
    a1.x += bf2f(v0.x); a1.y += bf2f(v0.y); a1.z += bf2f(v0.z); a1.w += bf2f(v0.w);
  }
  a0.x += (a1.x + a2.x) + a3.x;
  a0.y += (a1.y + a2.y) + a3.y;
  a0.z += (a1.z + a2.z) + a3.z;
  a0.w += (a1.w + a2.w) + a3.w;
  a0.x += __shfl_xor(a0.x, 32);
  a0.y += __shfl_xor(a0.y, 32);
  a0.z += __shfl_xor(a0.z, 32);
  a0.w += __shfl_xor(a0.w, 32);
  if (hw == 0) {
    ushort4 o = { f2bf(a0.x), f2bf(a0.y), f2bf(a0.z), f2bf(a0.w) };
    *(ushort4*)(out + (size_t)row*FD + off) = o;
  }
}

// MFMA bf16 GEMM: new[n,h] = [agg|cur][n,0:256] @ WB[h,0:256]^T + bias[h]
// 128x128 tile, BK=64, LDS row stride 72 bf16 (uniform bank load).
// BN relu-stats fused in epilogue. ty: 0=user update, 1=item update.
__global__ __launch_bounds__(256) void k_gemm(u16* __restrict__ aggU,
                                              u16* __restrict__ aggI,
                                              const u16* __restrict__ curU,
                                              const u16* __restrict__ curI,
                                              const u16* __restrict__ WBl,
                                              const float* __restrict__ bI2U,
                                              const float* __restrict__ bU2I,
                                              float* __restrict__ psum,
                                              float* __restrict__ psq) {
  __shared__ u16 As[128*72];
  __shared__ u16 Bs[128*72];
  __shared__ float Sred[2][4][128];
  int ty = blockIdx.y;
  u16* A1 = ty ? aggI : aggU;
  const u16* A2 = ty ? curI : curU;
  const u16* WBp = ty ? WBl : (WBl + 32768);
  const float* bias = ty ? bU2I : bI2U;
  int tid = threadIdx.x;
  int n0 = blockIdx.x * 128;
  int w = __builtin_amdgcn_readfirstlane(tid >> 6);
  int lane = tid & 63;
  int l15 = lane & 15;
  int quad = lane >> 4;
  f32x4 acc[2][8];
  #pragma unroll
  for (int tr = 0; tr < 2; tr++)
    #pragma unroll
    for (int tc = 0; tc < 8; tc++)
      acc[tr][tc] = (f32x4){0.f,0.f,0.f,0.f};

  for (int ch = 0; ch < 4; ch++) {
    const u16* Ap = (ch < 2) ? ((const u16*)A1 + ch*64) : (A2 + (ch-2)*64);
    #pragma unroll
    for (int i = 0; i < 4; i++) {
      int e = i*256 + tid;
      int r = e >> 3, seg = e & 7;
      int4 v = {0,0,0,0};
      int gr = n0 + r;
      if (gr < NN) v = *(const int4*)(Ap + (size_t)gr*FD + seg*8);
      *(int4*)&As[r*72 + seg*8] = v;
    }
    #pragma unroll
    for (int i = 0; i < 4; i++) {
      int e = i*256 + tid;
      int r = e >> 3, seg = e & 7;
      int4 v = *(const int4*)(WBp + r*256 + ch*64 + seg*8);
      *(int4*)&Bs[r*72 + seg*8] = v;
    }
    __syncthreads();
    #pragma unroll
    for (int ks = 0; ks < 2; ks++) {
      int kb = ks*32 + quad*8;
      short8 af0 = *(const short8*)&As[(w*32 + l15)*72 + kb];
      short8 af1 = *(const short8*)&As[(w*32 + 16 + l15)*72 + kb];
      short8 bf[8];
      #pragma unroll
      for (int tc = 0; tc < 8; tc++)
        bf[tc] = *(const short8*)&Bs[(tc*16 + l15)*72 + kb];
      #pragma unroll
      for (int tc = 0; tc < 8; tc++) {
        acc[0][tc] = __builtin_amdgcn_mfma_f32_16x16x32_bf16(af0, bf[tc], acc[0][tc], 0, 0, 0);
        acc[1][tc] = __builtin_amdgcn_mfma_f32_16x16x32_bf16(af1, bf[tc], acc[1][tc], 0, 0, 0);
      }
    }
    __syncthreads();
  }
  // epilogue: bias, bf16 store (in-place into A1), relu-stats
  float sv[8], qv[8], bj[8];
  #pragma unroll
  for (int tc = 0; tc < 8; tc++) {
    bj[tc] = bias[tc*16 + l15];
    sv[tc] = 0.f; qv[tc] = 0.f;
  }
  #pragma unroll
  for (int tr = 0; tr < 2; tr++) {
    int rbase = n0 + w*32 + tr*16 + quad*4;
    #pragma unroll
    for (int tc = 0; tc < 8; tc++) {
      int col = tc*16 + l15;
      #pragma unroll
      for (int g = 0; g < 4; g++) {
        int r = rbase + g;
        if (r < NN) {
          float v = acc[tr][tc][g] + bj[tc];
          float y = v > 0.f ? v : 0.f;
          sv[tc] += y; qv[tc] += y*y;
          A1[(size_t)r*FD + col] = f2bf(v);
        }
      }
    }
  }
  #pragma unroll
  for (int tc = 0; tc < 8; tc++) {
    sv[tc] += __shfl_xor(sv[tc], 16); qv[tc] += __shfl_xor(qv[tc], 16);
    sv[tc] += __shfl_xor(sv[tc], 32); qv[tc] += __shfl_xor(qv[tc], 32);
  }
  if (quad == 0) {
    #pragma unroll
    for (int tc = 0; tc < 8; tc++) {
      Sred[0][w][tc*16 + l15] = sv[tc];
      Sred[1][w][tc*16 + l15] = qv[tc];
    }
  }
  __syncthreads();
  if (tid < 128) {
    float s = Sred[0][0][tid] + Sred[0][1][tid] + Sred[0][2][tid] + Sred[0][3][tid];
    float q = Sred[1][0][tid] + Sred[1][1][tid] + Sred[1][2][tid] + Sred[1][3][tid];
    int o = (ty*NBLK + blockIdx.x)*FD + tid;
    psum[o] = s; psq[o] = q;
  }
}

__global__ __launch_bounds__(256) void k_bnfinal(const float* __restrict__ psum,
                                                 const float* __restrict__ psq,
                                                 const float* __restrict__ gu,
                                                 const float* __restrict__ bu,
                                                 const float* __restrict__ gi,
                                                 const float* __restrict__ bi,
                                                 float* __restrict__ bnsc,
                                                 float* __restrict__ bnsh) {
  int tid = threadIdx.x;
  int type = tid >> 7;            // 0=user, 1=item
  int c = tid & 127;
  int base = type*NBLK*FD + c;
  float s0=0.f,s1=0.f,s2p=0.f,s3=0.f,q0=0.f,q1=0.f,q2=0.f,q3=0.f;
  int b = 0;
  for (; b+4 <= NBLK; b += 4) {
    s0 += psum[base + (b+0)*FD]; q0 += psq[base + (b+0)*FD];
    s1 += psum[base + (b+1)*FD]; q1 += psq[base + (b+1)*FD];
    s2p += psum[base + (b+2)*FD]; q2 += psq[base + (b+2)*FD];
    s3 += psum[base + (b+3)*FD]; q3 += psq[base + (b+3)*FD];
  }
  for (; b < NBLK; b++) { s0 += psum[base + b*FD]; q0 += psq[base + b*FD]; }
  float s = (s0+s1)+(s2p+s3);
  float q = (q0+q1)+(q2+q3);
  float inv = 1.0f / (float)NN;
  float mean = s * inv;
  float var = q * inv - mean*mean;
  float rstd = rsqrtf(var + BNEPS);
  float g = type ? gi[c] : gu[c];
  float bb = type ? bi[c] : bu[c];
  float sc = rstd * g;
  bnsc[tid] = sc;
  bnsh[tid] = bb - mean * sc;
}

// BN-apply + fused mean-pool (batch ids sorted -> per-run register accumulation)
__global__ __launch_bounds__(256) void k_bnapply(const u16* __restrict__ newU,
                                                 const u16* __restrict__ newI,
                                                 const int* __restrict__ bu,
                                                 const int* __restrict__ bi,
                                                 const float* __restrict__ bnsc,
                                                 const float* __restrict__ bnsh,
                                                 const float* __restrict__ invcnt,
                                                 u16* __restrict__ xu,
                                                 u16* __restrict__ xi,
                                                 float* __restrict__ feats) {
  int type = blockIdx.y;          // 0=user, 1=item
  const u16* in = type ? newI : newU;
  const int* bt = type ? bi : bu;
  u16* out = type ? xi : xu;
  int tid = threadIdx.x;
  int c = tid & 127;
  int rh = tid >> 7;
  float sc = bnsc[type*128 + c];
  float sh = bnsh[type*128 + c];
  int rs = blockIdx.x*128 + rh*64;
  int re = rs + 64; if (re > NN) re = NN;
  if (rs >= re) return;
  int gcur = bt[rs];
  float acc = 0.f;
  for (int r = rs; r < re; r++) {
    int g = bt[r];
    if (g != gcur) {
      atomicAdd(&feats[(size_t)gcur*FD + c], acc * invcnt[gcur]);
      acc = 0.f; gcur = g;
    }
    float y = bf2f(in[(size_t)r*FD + c]);
    y = y > 0.f ? y : 0.f;
    float o = y * sc + sh;
    out[(size_t)r*FD + c] = f2bf(o);
    acc += o;
  }
  atomicAdd(&feats[(size_t)gcur*FD + c], acc * invcnt[gcur]);
}

__global__ __launch_bounds__(256) void k_heads(const float* __restrict__ feats,
                                               const float* __restrict__ fcW,
                                               const float* __restrict__ fcb,
                                               float* __restrict__ logits) {
  int idx = blockIdx.x*256 + threadIdx.x;
  if (idx >= LOGITS_N) return;
  int l = idx >> 13;
  int rem = idx & 8191;
  int g = rem >> 4;
  int c = rem & 15;
  const float* f = feats + ((size_t)l*NG + g)*FD;
  const float* w = fcW + ((size_t)l*NC + c)*FD;
  float s = 0.f;
  #pragma unroll
  for (int k = 0; k < FD; k += 4) {
    float4 fv = *(const float4*)(f + k);
    float4 wv = *(const float4*)(w + k);
    s += fv.x*wv.x + fv.y*wv.y + fv.z*wv.z + fv.w*wv.w;
  }
  logits[idx] = s + fcb[l*NC + c];
}

extern "C" void kernel_launch(void* const* d_in, const int* in_sizes, int n_in,
                              void* d_out, int out_size, void* d_ws, size_t ws_size,
                              hipStream_t stream) {
  const float* x_user   = (const float*)d_in[0];
  const float* x_item   = (const float*)d_in[1];
  const int*   eu2i     = (const int*)d_in[2];
  const int*   ei2u     = (const int*)d_in[3];
  const int*   bu       = (const int*)d_in[4];
  const int*   bi       = (const int*)d_in[5];
  const float* Wrel_u2i = (const float*)d_in[6];
  const float* Wroot_u2i= (const float*)d_in[7];
  const float* b_u2i    = (const float*)d_in[8];
  const float* Wrel_i2u = (const float*)d_in[9];
  const float* Wroot_i2u= (const float*)d_in[10];
  const float* b_i2u    = (const float*)d_in[11];
  const float* bn_g_user= (const float*)d_in[12];
  const float* bn_b_user= (const float*)d_in[13];
  const float* bn_g_item= (const float*)d_in[14];
  const float* bn_b_item= (const float*)d_in[15];
  const float* fcW      = (const float*)d_in[16];
  const float* fcb      = (const float*)d_in[17];

  char* ws = (char*)d_ws;
  int*   deg    = (int*)(ws + OFF_DEG);
  int*   gcnt   = (int*)(ws + OFF_GCNT);
  int*   rowptr = (int*)(ws + OFF_ROWPTR);
  int*   cursor = (int*)(ws + OFF_CURSOR);
  int*   bsum   = (int*)(ws + OFF_BSUM);
  float* invcnt = (float*)(ws + OFF_INVCNT);
  float* bnsc   = (float*)(ws + OFF_BNSC);
  float* bnsh   = (float*)(ws + OFF_BNSH);
  float* psum   = (float*)(ws + OFF_BNPART);
  float* psq    = psum + 2*NBLK*FD;
  u16*   WB     = (u16*)(ws + OFF_WB);
  int*   csr    = (int*)(ws + OFF_CSR);
  u16*   aggI   = (u16*)(ws + OFF_AGGI);
  u16*   aggU   = (u16*)(ws + OFF_AGGU);
  u16*   xu     = (u16*)(ws + OFF_XU);
  u16*   xi     = (u16*)(ws + OFF_XI);
  u16*   xu0    = (u16*)(ws + OFF_XU0);
  u16*   xi0    = (u16*)(ws + OFF_XI0);
  float* fout   = (float*)d_out;
  float* featsAll = fout + LOGITS_N;

  hipMemsetAsync(ws + OFF_DEG, 0, MEMSET_BYTES, stream);
  hipMemsetAsync(featsAll, 0, (size_t)NL*NG*FD*sizeof(float), stream);
  k_hist_edges<<<6250, 256, 0, stream>>>(eu2i, ei2u, deg);
  k_hist_batch<<<391, 256, 0, stream>>>(bu, bi, gcnt);
  k_blocksum<<<NBLK, 256, 0, stream>>>(deg, bsum);
  k_scanbsum<<<1, 512, 0, stream>>>(bsum);
  k_writerowptr<<<NBLK, 256, 0, stream>>>(deg, bsum, rowptr, cursor);
  k_invcnt<<<1, 512, 0, stream>>>(gcnt, invcnt);
  k_fill_csr<<<6250, 256, 0, stream>>>(eu2i, ei2u, cursor, csr);
  k_castX<<<12500, 256, 0, stream>>>(x_user, x_item, xu0, xi0);
  k_castW<<<768, 256, 0, stream>>>(Wrel_u2i, Wroot_u2i, Wrel_i2u, Wroot_i2u, WB);

  const u16* curU = xu0;
  const u16* curI = xi0;
  for (int l = 0; l < NL; l++) {
    k_gather<<<25000, 256, 0, stream>>>(curU, curI, rowptr, csr, aggI, aggU);
    k_gemm<<<dim3(NBLK,2), 256, 0, stream>>>(aggU, aggI, curU, curI,
                                             WB + (size_t)l*2*32768,
                                             b_i2u + l*FD, b_u2i + l*FD,
                                             psum, psq);
    k_bnfinal<<<1, 256, 0, stream>>>(psum, psq, bn_g_user, bn_b_user,
                                     bn_g_item, bn_b_item, bnsc, bnsh);
    k_bnapply<<<dim3(NBLK,2), 256, 0, stream>>>(aggU, aggI, bu, bi, bnsc, bnsh,
                                                invcnt, xu, xi,
                                                featsAll + (size_t)l*NG*FD);
    curU = xu; curI = xi;
  }
  k_heads<<<96, 256, 0, stream>>>(featsAll, fcW, fcb, fout);
}

// Round 4
// 680.624 us; speedup vs baseline: 2.5621x; 1.1614x over previous
//
#include <hip/hip_runtime.h>

#define NN 50000
#define FD 128
#define NE 800000
#define NG 512
#define NC 16
#define NL 3
#define NTOT 100000
#define NBLK 391            // ceil(100000/256) and ceil(50000/128)
#define NBUCK 196           // ceil(100000/512) slot-buckets
#define CAP 10240           // per-bucket capacity (avg 8192, sigma ~90)
#define BNEPS 1e-5f
#define LOGITS_N (NL*NG*NC)

typedef unsigned short u16;
typedef __attribute__((ext_vector_type(8))) short short8;
typedef __attribute__((ext_vector_type(4))) float f32x4;

// ---- workspace layout (bytes), offsets 512-aligned ----
#define OFF_DEG      0ul          // 100000 int
#define OFF_GCNT     400384ul     // 2*512 int
#define MEMSET_BYTES 404480ul     // covers DEG + GCNT
#define OFF_ROWPTR   409600ul     // 100001 int
#define OFF_BSUM     809984ul     // 512 int
#define OFF_BCUR     812544ul     // 196 int
#define OFF_INVCNT   813568ul     // 512 f32
#define OFF_BNSC     815616ul     // 256 f32
#define OFF_BNSH     816640ul     // 256 f32
#define OFF_BNPART   817664ul     // 2*(2*391*128) f32 (psum, psq)
#define OFF_WB       1618944ul    // 6*128*256 bf16
#define OFF_CSR      2012160ul    // 1600000 int
#define OFF_BINNED   8412160ul    // 196*10240 int2 = 16056320 B
#define OFF_AGGI     24468480ul   // 50000*128 bf16 (in-place -> new_i)
#define OFF_AGGU     37268480ul   // 50000*128 bf16 (in-place -> new_u)
#define OFF_XU       50068480ul   // 50000*128 bf16
#define OFF_XI       62868480ul   // 50000*128 bf16
#define OFF_XU0      75668480ul   // 50000*128 bf16 (initial cast)
#define OFF_XI0      88468480ul   // 50000*128 bf16

static __device__ __forceinline__ float bf2f(u16 v) {
  return __uint_as_float(((unsigned)v) << 16);
}
static __device__ __forceinline__ u16 f2bf(float f) {
  unsigned u = __float_as_uint(f);
  return (u16)((u + 0x7FFFu + ((u >> 16) & 1u)) >> 16);
}
// accumulate 8 packed bf16 (int4) into float[8]
static __device__ __forceinline__ void acc8(float* a, int4 v) {
  a[0] += __uint_as_float(((unsigned)v.x) << 16);
  a[1] += __uint_as_float(((unsigned)v.x) & 0xffff0000u);
  a[2] += __uint_as_float(((unsigned)v.y) << 16);
  a[3] += __uint_as_float(((unsigned)v.y) & 0xffff0000u);
  a[4] += __uint_as_float(((unsigned)v.z) << 16);
  a[5] += __uint_as_float(((unsigned)v.z) & 0xffff0000u);
  a[6] += __uint_as_float(((unsigned)v.w) << 16);
  a[7] += __uint_as_float(((unsigned)v.w) & 0xffff0000u);
}

__global__ __launch_bounds__(256) void k_init(int* __restrict__ bcursor) {
  int t = threadIdx.x;
  if (t < NBUCK) bcursor[t] = t * CAP;
}

__global__ __launch_bounds__(256) void k_hist_batch(const int* __restrict__ bu,
                                                    const int* __restrict__ bi,
                                                    int* __restrict__ gcnt) {
  int i = blockIdx.x*256 + threadIdx.x;
  if (i >= NTOT) return;
  int type = i >= NN;
  int g = type ? bi[i-NN] : bu[i];
  atomicAdd(&gcnt[type*NG + g], 1);
}

// bucket edges by dst-slot>>9 into fixed-capacity bucket regions (coalesced
// run writes via LDS reorder); per-slot degree histogram fused in.
__global__ __launch_bounds__(256) void k_bin(const int* __restrict__ eu2i,
                                             const int* __restrict__ ei2u,
                                             int* __restrict__ deg,
                                             int* __restrict__ bcursor,
                                             int2* __restrict__ binned) {
  __shared__ int hist[256];
  __shared__ int scan[256];
  __shared__ int gbase[256];
  __shared__ int2 rbuf[4096];
  int tid = threadIdx.x;
  int base = blockIdx.x * 4096;
  hist[tid] = 0;
  __syncthreads();
  int slotr[16], srcr[16], rankr[16];
  #pragma unroll
  for (int c = 0; c < 16; c++) {
    int idx = base + c*256 + tid;
    if (idx < 2*NE) {
      int rel = idx >= NE;
      int e = rel ? idx - NE : idx;
      const int* edge = rel ? ei2u : eu2i;
      int s = edge[e];
      int d = edge[NE + e];
      int slot = d + (rel ? NN : 0);
      slotr[c] = slot; srcr[c] = s;
      rankr[c] = atomicAdd(&hist[slot >> 9], 1);
      atomicAdd(&deg[slot], 1);
    } else slotr[c] = -1;
  }
  __syncthreads();
  scan[tid] = hist[tid];
  __syncthreads();
  for (int o = 1; o < 256; o <<= 1) {
    int v = (tid >= o) ? scan[tid - o] : 0;
    __syncthreads();
    scan[tid] += v;
    __syncthreads();
  }
  // scan[] = inclusive prefix of hist
  if (tid < NBUCK && hist[tid] > 0)
    gbase[tid] = atomicAdd(&bcursor[tid], hist[tid]);
  __syncthreads();
  #pragma unroll
  for (int c = 0; c < 16; c++) {
    if (slotr[c] >= 0) {
      int bk = slotr[c] >> 9;
      int lpos = scan[bk] - hist[bk] + rankr[c];
      rbuf[lpos] = make_int2(slotr[c], srcr[c]);
    }
  }
  __syncthreads();
  int nv = min(4096, 2*NE - base);
  for (int j = tid; j < nv; j += 256) {
    int2 pr = rbuf[j];
    int bk = pr.x >> 9;
    int outpos = gbase[bk] + (j - (scan[bk] - hist[bk]));
    binned[outpos] = pr;
  }
}

// one block per bucket: LDS-staged scatter -> coalesced CSR write-out
__global__ __launch_bounds__(256) void k_csrbuild(const int* __restrict__ rowptr,
                                                  const int2* __restrict__ binned,
                                                  int* __restrict__ csr) {
  __shared__ int lcur[512];
  __shared__ int lcsr[CAP];
  int b = blockIdx.x;
  int tid = threadIdx.x;
  int slot0 = b << 9;
  int nslots = min(512, NTOT - slot0);
  int rbase = rowptr[slot0];
  int rsize = rowptr[slot0 + nslots] - rbase;
  for (int s = tid; s < nslots; s += 256) lcur[s] = rowptr[slot0 + s] - rbase;
  __syncthreads();
  const int2* bp = binned + (size_t)b * CAP;
  for (int i = tid; i < rsize; i += 256) {
    int2 pr = bp[i];
    int pos = atomicAdd(&lcur[pr.x - slot0], 1);
    lcsr[pos] = pr.y;
  }
  __syncthreads();
  for (int i = tid; i < rsize; i += 256) csr[rbase + i] = lcsr[i];
}

// ---- parallel scan of deg[100000] -> rowptr ----
__global__ __launch_bounds__(256) void k_blocksum(const int* __restrict__ deg,
                                                  int* __restrict__ bsum) {
  int t = threadIdx.x;
  int idx = blockIdx.x*256 + t;
  int v = (idx < NTOT) ? deg[idx] : 0;
  __shared__ int red[4];
  #pragma unroll
  for (int o = 32; o; o >>= 1) v += __shfl_down(v, o);
  if ((t & 63) == 0) red[t >> 6] = v;
  __syncthreads();
  if (t == 0) bsum[blockIdx.x] = red[0] + red[1] + red[2] + red[3];
}

__global__ __launch_bounds__(512) void k_scanbsum(int* __restrict__ bsum) {
  __shared__ int s[512];
  int t = threadIdx.x;
  int v = (t < NBLK) ? bsum[t] : 0;
  s[t] = v;
  __syncthreads();
  for (int o = 1; o < 512; o <<= 1) {
    int u = (t >= o) ? s[t-o] : 0;
    __syncthreads();
    s[t] += u;
    __syncthreads();
  }
  if (t < NBLK) bsum[t] = s[t] - v;   // exclusive
}

__global__ __launch_bounds__(256) void k_writerowptr(const int* __restrict__ deg,
                                                     const int* __restrict__ bsum,
                                                     int* __restrict__ rowptr) {
  __shared__ int s[256];
  int t = threadIdx.x;
  int idx = blockIdx.x*256 + t;
  int v = (idx < NTOT) ? deg[idx] : 0;
  s[t] = v;
  __syncthreads();
  for (int o = 1; o < 256; o <<= 1) {
    int u = (t >= o) ? s[t-o] : 0;
    __syncthreads();
    s[t] += u;
    __syncthreads();
  }
  int excl = s[t] - v + bsum[blockIdx.x];
  if (idx < NTOT) rowptr[idx] = excl;
  if (idx == NTOT-1) rowptr[NTOT] = excl + v;
}

__global__ __launch_bounds__(512) void k_invcnt(const int* __restrict__ gcnt,
                                                float* __restrict__ invcnt) {
  int t = threadIdx.x;
  int c = gcnt[t] + gcnt[NG + t];
  invcnt[t] = 1.0f / (float)(c > 0 ? c : 1);
}

// fp32 -> bf16 cast of initial features
__global__ __launch_bounds__(256) void k_castX(const float* __restrict__ xu,
                                               const float* __restrict__ xi,
                                               u16* __restrict__ xbu,
                                               u16* __restrict__ xbi) {
  int b = blockIdx.x;
  int half = b >= 6250;
  const float* src = half ? xi : xu;
  u16* dst = half ? xbi : xbu;
  int i = ((half ? b - 6250 : b)*256 + threadIdx.x) * 4;
  float4 v = *(const float4*)(src + i);
  ushort4 o = { f2bf(v.x), f2bf(v.y), f2bf(v.z), f2bf(v.w) };
  *(ushort4*)(dst + i) = o;
}

// WB[lr][h][k]: k<128 -> Wrel[l][h][k], else Wroot[l][h][k-128]   (bf16)
__global__ __launch_bounds__(256) void k_castW(const float* __restrict__ WrelA,
                                               const float* __restrict__ WrootA,
                                               const float* __restrict__ WrelB,
                                               const float* __restrict__ WrootB,
                                               u16* __restrict__ WB) {
  int idx = blockIdx.x*256 + threadIdx.x;   // < 6*32768
  int lr = idx >> 15;
  int rem = idx & 32767;
  int h = rem >> 8;
  int k = rem & 255;
  int l = lr >> 1;
  int rel = lr & 1;
  const float* Wr = rel ? WrelB : WrelA;
  const float* Wo = rel ? WrootB : WrootA;
  float v = (k < FD) ? Wr[(l*FD + h)*FD + k] : Wo[(l*FD + h)*FD + (k-FD)];
  WB[idx] = f2bf(v);
}

// one wave per dst row; 16B/lane loads (16 lanes = one 256B row), quarter-waves
// take different edges; 2 chains x 8-edge iters with index prefetch.
// blocks [0,12500): u2i (curU -> aggI), [12500,25000): i2u (curI -> aggU)
__global__ __launch_bounds__(256) void k_gather(const u16* __restrict__ curU,
                                                const u16* __restrict__ curI,
                                                const int* __restrict__ rowptr,
                                                const int* __restrict__ csr,
                                                u16* __restrict__ aggI,
                                                u16* __restrict__ aggU) {
  int b = blockIdx.x;
  int half = b >= 12500;
  int blk = half ? b - 12500 : b;
  const u16* src = half ? curI : curU;
  u16* out = half ? aggU : aggI;
  int slotbase = half ? NN : 0;
  int wid = __builtin_amdgcn_readfirstlane(threadIdx.x >> 6);
  int row = blk*4 + wid;
  int lane = threadIdx.x & 63;
  int q = lane >> 4;
  int c16 = (lane & 15) * 8;      // 8 bf16 = 16B per lane
  const u16* sp = src + c16;
  const int* rp = rowptr + slotbase + row;
  int p = rp[0], pe = rp[1];
  float a0[8], a1[8];
  #pragma unroll
  for (int j = 0; j < 8; j++) { a0[j] = 0.f; a1[j] = 0.f; }
  if (p + 8 <= pe) {
    int i0 = csr[p + q], i1 = csr[p + 4 + q];
    while (p + 16 <= pe) {
      int n0 = csr[p + 8 + q], n1 = csr[p + 12 + q];
      int4 v0 = *(const int4*)(sp + (size_t)i0*FD);
      int4 v1 = *(const int4*)(sp + (size_t)i1*FD);
      acc8(a0, v0); acc8(a1, v1);
      i0 = n0; i1 = n1; p += 8;
    }
    int4 v0 = *(const int4*)(sp + (size_t)i0*FD);
    int4 v1 = *(const int4*)(sp + (size_t)i1*FD);
    acc8(a0, v0); acc8(a1, v1);
    p += 8;
  }
  int rem = pe - p;               // 0..7
  if (q < rem) {
    int s = csr[p + q];
    acc8(a0, *(const int4*)(sp + (size_t)s*FD));
  }
  if (q + 4 < rem) {
    int s = csr[p + 4 + q];
    acc8(a1, *(const int4*)(sp + (size_t)s*FD));
  }
  #pragma unroll
  for (int j = 0; j < 8; j++) a0[j] += a1[j];
  #pragma unroll
  for (int j = 0; j < 8; j++) {
    a0[j] += __shfl_xor(a0[j], 16);
    a0[j] += __shfl_xor(a0[j], 32);
  }
  if (q == 0) {
    int4 o;
    o.x = (unsigned)f2bf(a0[0]) | ((unsigned)f2bf(a0[1]) << 16);
    o.y = (unsigned)f2bf(a0[2]) | ((unsigned)f2bf(a0[3]) << 16);
    o.z = (unsigned)f2bf(a0[4]) | ((unsigned)f2bf(a0[5]) << 16);
    o.w = (unsigned)f2bf(a0[6]) | ((unsigned)f2bf(a0[7]) << 16);
    *(int4*)(out + (size_t)row*FD + c16) = o;
  }
}

// MFMA bf16 GEMM: new[n,h] = [agg|cur][n,0:256] @ WB[h,0:256]^T + bias[h]
// 128x128 tile, BK=64, LDS row stride 72 bf16. BN relu-stats fused in epilogue.
__global__ __launch_bounds__(256) void k_gemm(u16* __restrict__ aggU,
                                              u16* __restrict__ aggI,
                                              const u16* __restrict__ curU,
                                              const u16* __restrict__ curI,
                                              const u16* __restrict__ WBl,
                                              const float* __restrict__ bI2U,
                                              const float* __restrict__ bU2I,
                                              float* __restrict__ psum,
                                              float* __restrict__ psq) {
  __shared__ u16 As[128*72];
  __shared__ u16 Bs[128*72];
  __shared__ float Sred[2][4][128];
  int ty = blockIdx.y;
  u16* A1 = ty ? aggI : aggU;
  const u16* A2 = ty ? curI : curU;
  const u16* WBp = ty ? WBl : (WBl + 32768);
  const float* bias = ty ? bU2I : bI2U;
  int tid = threadIdx.x;
  int n0 = blockIdx.x * 128;
  int w = __builtin_amdgcn_readfirstlane(tid >> 6);
  int lane = tid & 63;
  int l15 = lane & 15;
  int quad = lane >> 4;
  f32x4 acc[2][8];
  #pragma unroll
  for (int tr = 0; tr < 2; tr++)
    #pragma unroll
    for (int tc = 0; tc < 8; tc++)
      acc[tr][tc] = (f32x4){0.f,0.f,0.f,0.f};

  for (int ch = 0; ch < 4; ch++) {
    const u16* Ap = (ch < 2) ? ((const u16*)A1 + ch*64) : (A2 + (ch-2)*64);
    #pragma unroll
    for (int i = 0; i < 4; i++) {
      int e = i*256 + tid;
      int r = e >> 3, seg = e & 7;
      int4 v = {0,0,0,0};
      int gr = n0 + r;
      if (gr < NN) v = *(const int4*)(Ap + (size_t)gr*FD + seg*8);
      *(int4*)&As[r*72 + seg*8] = v;
    }
    #pragma unroll
    for (int i = 0; i < 4; i++) {
      int e = i*256 + tid;
      int r = e >> 3, seg = e & 7;
      int4 v = *(const int4*)(WBp + r*256 + ch*64 + seg*8);
      *(int4*)&Bs[r*72 + seg*8] = v;
    }
    __syncthreads();
    #pragma unroll
    for (int ks = 0; ks < 2; ks++) {
      int kb = ks*32 + quad*8;
      short8 af0 = *(const short8*)&As[(w*32 + l15)*72 + kb];
      short8 af1 = *(const short8*)&As[(w*32 + 16 + l15)*72 + kb];
      short8 bf[8];
      #pragma unroll
      for (int tc = 0; tc < 8; tc++)
        bf[tc] = *(const short8*)&Bs[(tc*16 + l15)*72 + kb];
      #pragma unroll
      for (int tc = 0; tc < 8; tc++) {
        acc[0][tc] = __builtin_amdgcn_mfma_f32_16x16x32_bf16(af0, bf[tc], acc[0][tc], 0, 0, 0);
        acc[1][tc] = __builtin_amdgcn_mfma_f32_16x16x32_bf16(af1, bf[tc], acc[1][tc], 0, 0, 0);
      }
    }
    __syncthreads();
  }
  float sv[8], qv[8], bj[8];
  #pragma unroll
  for (int tc = 0; tc < 8; tc++) {
    bj[tc] = bias[tc*16 + l15];
    sv[tc] = 0.f; qv[tc] = 0.f;
  }
  #pragma unroll
  for (int tr = 0; tr < 2; tr++) {
    int rbase = n0 + w*32 + tr*16 + quad*4;
    #pragma unroll
    for (int tc = 0; tc < 8; tc++) {
      int col = tc*16 + l15;
      #pragma unroll
      for (int g = 0; g < 4; g++) {
        int r = rbase + g;
        if (r < NN) {
          float v = acc[tr][tc][g] + bj[tc];
          float y = v > 0.f ? v : 0.f;
          sv[tc] += y; qv[tc] += y*y;
          A1[(size_t)r*FD + col] = f2bf(v);
        }
      }
    }
  }
  #pragma unroll
  for (int tc = 0; tc < 8; tc++) {
    sv[tc] += __shfl_xor(sv[tc], 16); qv[tc] += __shfl_xor(qv[tc], 16);
    sv[tc] += __shfl_xor(sv[tc], 32); qv[tc] += __shfl_xor(qv[tc], 32);
  }
  if (quad == 0) {
    #pragma unroll
    for (int tc = 0; tc < 8; tc++) {
      Sred[0][w][tc*16 + l15] = sv[tc];
      Sred[1][w][tc*16 + l15] = qv[tc];
    }
  }
  __syncthreads();
  if (tid < 128) {
    float s = Sred[0][0][tid] + Sred[0][1][tid] + Sred[0][2][tid] + Sred[0][3][tid];
    float q = Sred[1][0][tid] + Sred[1][1][tid] + Sred[1][2][tid] + Sred[1][3][tid];
    int o = (ty*NBLK + blockIdx.x)*FD + tid;
    psum[o] = s; psq[o] = q;
  }
}

__global__ __launch_bounds__(256) void k_bnfinal(const float* __restrict__ psum,
                                                 const float* __restrict__ psq,
                                                 const float* __restrict__ gu,
                                                 const float* __restrict__ bu,
                                                 const float* __restrict__ gi,
                                                 const float* __restrict__ bi,
                                                 float* __restrict__ bnsc,
                                                 float* __restrict__ bnsh) {
  int tid = threadIdx.x;
  int type = tid >> 7;            // 0=user, 1=item
  int c = tid & 127;
  int base = type*NBLK*FD + c;
  float s0=0.f,s1=0.f,s2p=0.f,s3=0.f,q0=0.f,q1=0.f,q2=0.f,q3=0.f;
  int b = 0;
  for (; b+4 <= NBLK; b += 4) {
    s0 += psum[base + (b+0)*FD]; q0 += psq[base + (b+0)*FD];
    s1 += psum[base + (b+1)*FD]; q1 += psq[base + (b+1)*FD];
    s2p += psum[base + (b+2)*FD]; q2 += psq[base + (b+2)*FD];
    s3 += psum[base + (b+3)*FD]; q3 += psq[base + (b+3)*FD];
  }
  for (; b < NBLK; b++) { s0 += psum[base + b*FD]; q0 += psq[base + b*FD]; }
  float s = (s0+s1)+(s2p+s3);
  float q = (q0+q1)+(q2+q3);
  float inv = 1.0f / (float)NN;
  float mean = s * inv;
  float var = q * inv - mean*mean;
  float rstd = rsqrtf(var + BNEPS);
  float g = type ? gi[c] : gu[c];
  float bb = type ? bi[c] : bu[c];
  float sc = rstd * g;
  bnsc[tid] = sc;
  bnsh[tid] = bb - mean * sc;
}

// BN-apply + fused mean-pool (batch ids sorted -> per-run register accumulation)
__global__ __launch_bounds__(256) void k_bnapply(const u16* __restrict__ newU,
                                                 const u16* __restrict__ newI,
                                                 const int* __restrict__ bu,
                                                 const int* __restrict__ bi,
                                                 const float* __restrict__ bnsc,
                                                 const float* __restrict__ bnsh,
                                                 const float* __restrict__ invcnt,
                                                 u16* __restrict__ xu,
                                                 u16* __restrict__ xi,
                                                 float* __restrict__ feats) {
  int type = blockIdx.y;          // 0=user, 1=item
  const u16* in = type ? newI : newU;
  const int* bt = type ? bi : bu;
  u16* out = type ? xi : xu;
  int tid = threadIdx.x;
  int c = tid & 127;
  int rh = tid >> 7;
  float sc = bnsc[type*128 + c];
  float sh = bnsh[type*128 + c];
  int rs = blockIdx.x*128 + rh*64;
  int re = rs + 64; if (re > NN) re = NN;
  if (rs >= re) return;
  int gcur = bt[rs];
  float acc = 0.f;
  for (int r = rs; r < re; r++) {
    int g = bt[r];
    if (g != gcur) {
      atomicAdd(&feats[(size_t)gcur*FD + c], acc * invcnt[gcur]);
      acc = 0.f; gcur = g;
    }
    float y = bf2f(in[(size_t)r*FD + c]);
    y = y > 0.f ? y : 0.f;
    float o = y * sc + sh;
    out[(size_t)r*FD + c] = f2bf(o);
    acc += o;
  }
  atomicAdd(&feats[(size_t)gcur*FD + c], acc * invcnt[gcur]);
}

__global__ __launch_bounds__(256) void k_heads(const float* __restrict__ feats,
                                               const float* __restrict__ fcW,
                                               const float* __restrict__ fcb,
                                               float* __restrict__ logits) {
  int idx = blockIdx.x*256 + threadIdx.x;
  if (idx >= LOGITS_N) return;
  int l = idx >> 13;
  int rem = idx & 8191;
  int g = rem >> 4;
  int c = rem & 15;
  const float* f = feats + ((size_t)l*NG + g)*FD;
  const float* w = fcW + ((size_t)l*NC + c)*FD;
  float s = 0.f;
  #pragma unroll
  for (int k = 0; k < FD; k += 4) {
    float4 fv = *(const float4*)(f + k);
    float4 wv = *(const float4*)(w + k);
    s += fv.x*wv.x + fv.y*wv.y + fv.z*wv.z + fv.w*wv.w;
  }
  logits[idx] = s + fcb[l*NC + c];
}

extern "C" void kernel_launch(void* const* d_in, const int* in_sizes, int n_in,
                              void* d_out, int out_size, void* d_ws, size_t ws_size,
                              hipStream_t stream) {
  const float* x_user   = (const float*)d_in[0];
  const float* x_item   = (const float*)d_in[1];
  const int*   eu2i     = (const int*)d_in[2];
  const int*   ei2u     = (const int*)d_in[3];
  const int*   bu       = (const int*)d_in[4];
  const int*   bi       = (const int*)d_in[5];
  const float* Wrel_u2i = (const float*)d_in[6];
  const float* Wroot_u2i= (const float*)d_in[7];
  const float* b_u2i    = (const float*)d_in[8];
  const float* Wrel_i2u = (const float*)d_in[9];
  const float* Wroot_i2u= (const float*)d_in[10];
  const float* b_i2u    = (const float*)d_in[11];
  const float* bn_g_user= (const float*)d_in[12];
  const float* bn_b_user= (const float*)d_in[13];
  const float* bn_g_item= (const float*)d_in[14];
  const float* bn_b_item= (const float*)d_in[15];
  const float* fcW      = (const float*)d_in[16];
  const float* fcb      = (const float*)d_in[17];

  char* ws = (char*)d_ws;
  int*   deg    = (int*)(ws + OFF_DEG);
  int*   gcnt   = (int*)(ws + OFF_GCNT);
  int*   rowptr = (int*)(ws + OFF_ROWPTR);
  int*   bsum   = (int*)(ws + OFF_BSUM);
  int*   bcursor= (int*)(ws + OFF_BCUR);
  float* invcnt = (float*)(ws + OFF_INVCNT);
  float* bnsc   = (float*)(ws + OFF_BNSC);
  float* bnsh   = (float*)(ws + OFF_BNSH);
  float* psum   = (float*)(ws + OFF_BNPART);
  float* psq    = psum + 2*NBLK*FD;
  u16*   WB     = (u16*)(ws + OFF_WB);
  int*   csr    = (int*)(ws + OFF_CSR);
  int2*  binned = (int2*)(ws + OFF_BINNED);
  u16*   aggI   = (u16*)(ws + OFF_AGGI);
  u16*   aggU   = (u16*)(ws + OFF_AGGU);
  u16*   xu     = (u16*)(ws + OFF_XU);
  u16*   xi     = (u16*)(ws + OFF_XI);
  u16*   xu0    = (u16*)(ws + OFF_XU0);
  u16*   xi0    = (u16*)(ws + OFF_XI0);
  float* fout   = (float*)d_out;
  float* featsAll = fout + LOGITS_N;

  hipMemsetAsync(ws + OFF_DEG, 0, MEMSET_BYTES, stream);
  hipMemsetAsync(featsAll, 0, (size_t)NL*NG*FD*sizeof(float), stream);
  k_init<<<1, 256, 0, stream>>>(bcursor);
  k_hist_batch<<<NBLK, 256, 0, stream>>>(bu, bi, gcnt);
  k_bin<<<391, 256, 0, stream>>>(eu2i, ei2u, deg, bcursor, binned);
  k_blocksum<<<NBLK, 256, 0, stream>>>(deg, bsum);
  k_scanbsum<<<1, 512, 0, stream>>>(bsum);
  k_writerowptr<<<NBLK, 256, 0, stream>>>(deg, bsum, rowptr);
  k_invcnt<<<1, 512, 0, stream>>>(gcnt, invcnt);
  k_csrbuild<<<NBUCK, 256, 0, stream>>>(rowptr, binned, csr);
  k_castX<<<12500, 256, 0, stream>>>(x_user, x_item, xu0, xi0);
  k_castW<<<768, 256, 0, stream>>>(Wrel_u2i, Wroot_u2i, Wrel_i2u, Wroot_i2u, WB);

  const u16* curU = xu0;
  const u16* curI = xi0;
  for (int l = 0; l < NL; l++) {
    k_gather<<<25000, 256, 0, stream>>>(curU, curI, rowptr, csr, aggI, aggU);
    k_gemm<<<dim3(NBLK,2), 256, 0, stream>>>(aggU, aggI, curU, curI,
                                             WB + (size_t)l*2*32768,
                                             b_i2u + l*FD, b_u2i + l*FD,
                                             psum, psq);
    k_bnfinal<<<1, 256, 0, stream>>>(psum, psq, bn_g_user, bn_b_user,
                                     bn_g_item, bn_b_item, bnsc, bnsh);
    k_bnapply<<<dim3(NBLK,2), 256, 0, stream>>>(aggU, aggI, bu, bi, bnsc, bnsh,
                                                invcnt, xu, xi,
                                                featsAll + (size_t)l*NG*FD);
    curU = xu; curI = xi;
  }
  k_heads<<<96, 256, 0, stream>>>(featsAll, fcW, fcb, fout);
}

// Round 5
// 597.874 us; speedup vs baseline: 2.9167x; 1.1384x over previous
//
#include <hip/hip_runtime.h>

#define NN 50000
#define FD 128
#define NE 800000
#define NG 512
#define NC 16
#define NL 3
#define NTOT 100000
#define NBLK 391            // ceil(100000/256) and ceil(50000/128)
#define NBUCK 196           // ceil(100000/512) slot-buckets
#define CAP 10240           // per-bucket capacity (avg 8163, sigma ~90)
#define BNEPS 1e-5f
#define LOGITS_N (NL*NG*NC)

typedef unsigned short u16;
typedef unsigned char u8;
typedef __attribute__((ext_vector_type(8))) short short8;
typedef __attribute__((ext_vector_type(4))) float f32x4;

// ---- workspace layout (bytes), offsets 512-aligned ----
#define OFF_GCNT     0ul          // 2*512 int
#define OFF_BCUR     4096ul       // 196 int (per-bucket fill count)
#define OFF_ACC      5120ul       // 512 f32 (BN stat accumulators: S[256],Q[256])
#define MEMSET_BYTES 7168ul       // covers GCNT + BCUR + ACC
#define OFF_ROWRANGE 7680ul       // 100000 int2
#define OFF_INVCNT   808448ul     // 512 f32
#define OFF_BNSC     810496ul     // 256 f32
#define OFF_BNSH     811520ul     // 256 f32
#define OFF_WB       812544ul     // 6*128*256 bf16
#define OFF_CSR      1205760ul    // 196*10240 int (binned, then CSR in place)
#define OFF_AGGI     9233920ul    // 50000*128 bf16 (in-place -> new_i)
#define OFF_AGGU     22033920ul   // 50000*128 bf16 (in-place -> new_u)
#define OFF_XU       34833920ul   // 50000*128 bf16
#define OFF_XI       47633920ul   // 50000*128 bf16
#define OFF_XU0      60433920ul   // 50000*128 bf16 (initial cast)
#define OFF_XI0      73233920ul   // 50000*128 bf16

static __device__ __forceinline__ float bf2f(u16 v) {
  return __uint_as_float(((unsigned)v) << 16);
}
static __device__ __forceinline__ u16 f2bf(float f) {
  unsigned u = __float_as_uint(f);
  return (u16)((u + 0x7FFFu + ((u >> 16) & 1u)) >> 16);
}
// accumulate 8 packed bf16 (int4) into float[8]
static __device__ __forceinline__ void acc8(float* a, int4 v) {
  a[0] += __uint_as_float(((unsigned)v.x) << 16);
  a[1] += __uint_as_float(((unsigned)v.x) & 0xffff0000u);
  a[2] += __uint_as_float(((unsigned)v.y) << 16);
  a[3] += __uint_as_float(((unsigned)v.y) & 0xffff0000u);
  a[4] += __uint_as_float(((unsigned)v.z) << 16);
  a[5] += __uint_as_float(((unsigned)v.z) & 0xffff0000u);
  a[6] += __uint_as_float(((unsigned)v.w) << 16);
  a[7] += __uint_as_float(((unsigned)v.w) & 0xffff0000u);
}

__global__ __launch_bounds__(256) void k_hist_batch(const int* __restrict__ bu,
                                                    const int* __restrict__ bi,
                                                    int* __restrict__ gcnt) {
  int i = blockIdx.x*256 + threadIdx.x;
  if (i >= NTOT) return;
  int type = i >= NN;
  int g = type ? bi[i-NN] : bu[i];
  atomicAdd(&gcnt[type*NG + g], 1);
}

__global__ __launch_bounds__(512) void k_invcnt(const int* __restrict__ gcnt,
                                                float* __restrict__ invcnt) {
  int t = threadIdx.x;
  int c = gcnt[t] + gcnt[NG + t];
  invcnt[t] = 1.0f / (float)(c > 0 ? c : 1);
}

// bucket edges by dst-slot>>9 into fixed-capacity regions. Entry packed to 4B:
// (lslot:9 | src:17). Coalesced run writes via LDS reorder.
__global__ __launch_bounds__(256) void k_bin(const int* __restrict__ eu2i,
                                             const int* __restrict__ ei2u,
                                             int* __restrict__ bcursor,
                                             int* __restrict__ binned) {
  __shared__ int hist[256];
  __shared__ int scan[256];
  __shared__ int gbase[256];
  __shared__ int rbuf[4096];
  __shared__ u8 rbk[4096];
  int tid = threadIdx.x;
  int base = blockIdx.x * 4096;
  hist[tid] = 0;
  __syncthreads();
  int packr[16], bkr[16], rankr[16];
  #pragma unroll
  for (int c = 0; c < 16; c++) {
    int idx = base + c*256 + tid;
    if (idx < 2*NE) {
      int rel = idx >= NE;
      int e = rel ? idx - NE : idx;
      const int* edge = rel ? ei2u : eu2i;
      int s = edge[e];
      int d = edge[NE + e];
      int slot = d + (rel ? NN : 0);
      int bk = slot >> 9;
      bkr[c] = bk;
      packr[c] = ((slot & 511) << 17) | s;
      rankr[c] = atomicAdd(&hist[bk], 1);
    } else bkr[c] = -1;
  }
  __syncthreads();
  scan[tid] = hist[tid];
  __syncthreads();
  for (int o = 1; o < 256; o <<= 1) {
    int v = (tid >= o) ? scan[tid - o] : 0;
    __syncthreads();
    scan[tid] += v;
    __syncthreads();
  }
  if (tid < NBUCK && hist[tid] > 0)
    gbase[tid] = atomicAdd(&bcursor[tid], hist[tid]);
  __syncthreads();
  #pragma unroll
  for (int c = 0; c < 16; c++) {
    if (bkr[c] >= 0) {
      int bk = bkr[c];
      int lpos = scan[bk] - hist[bk] + rankr[c];
      rbuf[lpos] = packr[c];
      rbk[lpos] = (u8)bk;
    }
  }
  __syncthreads();
  int nv = min(4096, 2*NE - base);
  for (int j = tid; j < nv; j += 256) {
    int bk = rbk[j];
    int outpos = bk*CAP + gbase[bk] + (j - (scan[bk] - hist[bk]));
    binned[outpos] = rbuf[j];
  }
}

// one block per bucket: local hist+scan -> rowrange, LDS-staged scatter,
// CSR written IN PLACE over the binned region (block-private).
__global__ __launch_bounds__(256) void k_csrbuild(const int* __restrict__ bcursor,
                                                  int* __restrict__ csrbin,
                                                  int2* __restrict__ rowrange) {
  __shared__ int lcnt[512];
  __shared__ int scan2[256];
  __shared__ int lcsr[CAP];
  int b = blockIdx.x;
  int tid = threadIdx.x;
  int slot0 = b << 9;
  int nslots = min(512, NTOT - slot0);
  int n = bcursor[b];
  int gb = b * CAP;
  lcnt[tid] = 0; lcnt[tid + 256] = 0;
  __syncthreads();
  for (int i = tid; i < n; i += 256) {
    int e = csrbin[gb + i];
    atomicAdd(&lcnt[e >> 17], 1);
  }
  __syncthreads();
  int v0 = lcnt[2*tid], v1 = lcnt[2*tid + 1];
  int ps = v0 + v1;
  scan2[tid] = ps;
  __syncthreads();
  for (int o = 1; o < 256; o <<= 1) {
    int v = (tid >= o) ? scan2[tid - o] : 0;
    __syncthreads();
    scan2[tid] += v;
    __syncthreads();
  }
  int e0 = scan2[tid] - ps;       // exclusive prefix for slot 2*tid
  int e1 = e0 + v0;
  if (2*tid < nslots)     rowrange[slot0 + 2*tid]     = make_int2(gb + e0, gb + e0 + v0);
  if (2*tid + 1 < nslots) rowrange[slot0 + 2*tid + 1] = make_int2(gb + e1, gb + e1 + v1);
  __syncthreads();
  lcnt[2*tid] = e0; lcnt[2*tid + 1] = e1;   // cursors
  __syncthreads();
  for (int i = tid; i < n; i += 256) {
    int e = csrbin[gb + i];
    int pos = atomicAdd(&lcnt[e >> 17], 1);
    lcsr[pos] = e & 0x1FFFF;
  }
  __syncthreads();
  for (int i = tid; i < n; i += 256) csrbin[gb + i] = lcsr[i];
}

// fp32 -> bf16 cast of initial features
__global__ __launch_bounds__(256) void k_castX(const float* __restrict__ xu,
                                               const float* __restrict__ xi,
                                               u16* __restrict__ xbu,
                                               u16* __restrict__ xbi) {
  int b = blockIdx.x;
  int half = b >= 6250;
  const float* src = half ? xi : xu;
  u16* dst = half ? xbi : xbu;
  int i = ((half ? b - 6250 : b)*256 + threadIdx.x) * 4;
  float4 v = *(const float4*)(src + i);
  ushort4 o = { f2bf(v.x), f2bf(v.y), f2bf(v.z), f2bf(v.w) };
  *(ushort4*)(dst + i) = o;
}

// WB[lr][h][k]: k<128 -> Wrel[l][h][k], else Wroot[l][h][k-128]   (bf16)
__global__ __launch_bounds__(256) void k_castW(const float* __restrict__ WrelA,
                                               const float* __restrict__ WrootA,
                                               const float* __restrict__ WrelB,
                                               const float* __restrict__ WrootB,
                                               u16* __restrict__ WB) {
  int idx = blockIdx.x*256 + threadIdx.x;   // < 6*32768
  int lr = idx >> 15;
  int rem = idx & 32767;
  int h = rem >> 8;
  int k = rem & 255;
  int l = lr >> 1;
  int rel = lr & 1;
  const float* Wr = rel ? WrelB : WrelA;
  const float* Wo = rel ? WrootB : WrootA;
  float v = (k < FD) ? Wr[(l*FD + h)*FD + k] : Wo[(l*FD + h)*FD + (k-FD)];
  WB[idx] = f2bf(v);
}

// one wave per dst row; 16B/lane loads (16 lanes = one 256B row), quarter-waves
// take different edges; 2 chains x 8-edge iters with index prefetch.
// blocks [0,12500): u2i (curU -> aggI), [12500,25000): i2u (curI -> aggU)
__global__ __launch_bounds__(256) void k_gather(const u16* __restrict__ curU,
                                                const u16* __restrict__ curI,
                                                const int2* __restrict__ rowrange,
                                                const int* __restrict__ csr,
                                                u16* __restrict__ aggI,
                                                u16* __restrict__ aggU) {
  int b = blockIdx.x;
  int half = b >= 12500;
  int blk = half ? b - 12500 : b;
  const u16* src = half ? curI : curU;
  u16* out = half ? aggU : aggI;
  int slotbase = half ? NN : 0;
  int wid = __builtin_amdgcn_readfirstlane(threadIdx.x >> 6);
  int row = blk*4 + wid;
  int lane = threadIdx.x & 63;
  int q = lane >> 4;
  int c16 = (lane & 15) * 8;      // 8 bf16 = 16B per lane
  const u16* sp = src + c16;
  int2 pr = rowrange[slotbase + row];
  int p = pr.x, pe = pr.y;
  float a0[8], a1[8];
  #pragma unroll
  for (int j = 0; j < 8; j++) { a0[j] = 0.f; a1[j] = 0.f; }
  if (p + 8 <= pe) {
    int i0 = csr[p + q], i1 = csr[p + 4 + q];
    while (p + 16 <= pe) {
      int n0 = csr[p + 8 + q], n1 = csr[p + 12 + q];
      int4 v0 = *(const int4*)(sp + (size_t)i0*FD);
      int4 v1 = *(const int4*)(sp + (size_t)i1*FD);
      acc8(a0, v0); acc8(a1, v1);
      i0 = n0; i1 = n1; p += 8;
    }
    int4 v0 = *(const int4*)(sp + (size_t)i0*FD);
    int4 v1 = *(const int4*)(sp + (size_t)i1*FD);
    acc8(a0, v0); acc8(a1, v1);
    p += 8;
  }
  int rem = pe - p;               // 0..7
  if (q < rem) {
    int s = csr[p + q];
    acc8(a0, *(const int4*)(sp + (size_t)s*FD));
  }
  if (q + 4 < rem) {
    int s = csr[p + 4 + q];
    acc8(a1, *(const int4*)(sp + (size_t)s*FD));
  }
  #pragma unroll
  for (int j = 0; j < 8; j++) a0[j] += a1[j];
  #pragma unroll
  for (int j = 0; j < 8; j++) {
    a0[j] += __shfl_xor(a0[j], 16);
    a0[j] += __shfl_xor(a0[j], 32);
  }
  if (q == 0) {
    int4 o;
    o.x = (unsigned)f2bf(a0[0]) | ((unsigned)f2bf(a0[1]) << 16);
    o.y = (unsigned)f2bf(a0[2]) | ((unsigned)f2bf(a0[3]) << 16);
    o.z = (unsigned)f2bf(a0[4]) | ((unsigned)f2bf(a0[5]) << 16);
    o.w = (unsigned)f2bf(a0[6]) | ((unsigned)f2bf(a0[7]) << 16);
    *(int4*)(out + (size_t)row*FD + c16) = o;
  }
}

// MFMA bf16 GEMM: new[n,h] = [agg|cur][n,0:256] @ WB[h,0:256]^T + bias[h]
// 128x128 tile, BK=64, LDS row stride 72 bf16. BN relu-stats -> global atomics.
__global__ __launch_bounds__(256) void k_gemm(u16* __restrict__ aggU,
                                              u16* __restrict__ aggI,
                                              const u16* __restrict__ curU,
                                              const u16* __restrict__ curI,
                                              const u16* __restrict__ WBl,
                                              const float* __restrict__ bI2U,
                                              const float* __restrict__ bU2I,
                                              float* __restrict__ accSQ) {
  __shared__ u16 As[128*72];
  __shared__ u16 Bs[128*72];
  __shared__ float Sred[2][4][128];
  int ty = blockIdx.y;
  u16* A1 = ty ? aggI : aggU;
  const u16* A2 = ty ? curI : curU;
  const u16* WBp = ty ? WBl : (WBl + 32768);
  const float* bias = ty ? bU2I : bI2U;
  int tid = threadIdx.x;
  int n0 = blockIdx.x * 128;
  int w = __builtin_amdgcn_readfirstlane(tid >> 6);
  int lane = tid & 63;
  int l15 = lane & 15;
  int quad = lane >> 4;
  f32x4 acc[2][8];
  #pragma unroll
  for (int tr = 0; tr < 2; tr++)
    #pragma unroll
    for (int tc = 0; tc < 8; tc++)
      acc[tr][tc] = (f32x4){0.f,0.f,0.f,0.f};

  for (int ch = 0; ch < 4; ch++) {
    const u16* Ap = (ch < 2) ? ((const u16*)A1 + ch*64) : (A2 + (ch-2)*64);
    #pragma unroll
    for (int i = 0; i < 4; i++) {
      int e = i*256 + tid;
      int r = e >> 3, seg = e & 7;
      int4 v = {0,0,0,0};
      int gr = n0 + r;
      if (gr < NN) v = *(const int4*)(Ap + (size_t)gr*FD + seg*8);
      *(int4*)&As[r*72 + seg*8] = v;
    }
    #pragma unroll
    for (int i = 0; i < 4; i++) {
      int e = i*256 + tid;
      int r = e >> 3, seg = e & 7;
      int4 v = *(const int4*)(WBp + r*256 + ch*64 + seg*8);
      *(int4*)&Bs[r*72 + seg*8] = v;
    }
    __syncthreads();
    #pragma unroll
    for (int ks = 0; ks < 2; ks++) {
      int kb = ks*32 + quad*8;
      short8 af0 = *(const short8*)&As[(w*32 + l15)*72 + kb];
      short8 af1 = *(const short8*)&As[(w*32 + 16 + l15)*72 + kb];
      short8 bf[8];
      #pragma unroll
      for (int tc = 0; tc < 8; tc++)
        bf[tc] = *(const short8*)&Bs[(tc*16 + l15)*72 + kb];
      #pragma unroll
      for (int tc = 0; tc < 8; tc++) {
        acc[0][tc] = __builtin_amdgcn_mfma_f32_16x16x32_bf16(af0, bf[tc], acc[0][tc], 0, 0, 0);
        acc[1][tc] = __builtin_amdgcn_mfma_f32_16x16x32_bf16(af1, bf[tc], acc[1][tc], 0, 0, 0);
      }
    }
    __syncthreads();
  }
  float sv[8], qv[8], bj[8];
  #pragma unroll
  for (int tc = 0; tc < 8; tc++) {
    bj[tc] = bias[tc*16 + l15];
    sv[tc] = 0.f; qv[tc] = 0.f;
  }
  #pragma unroll
  for (int tr = 0; tr < 2; tr++) {
    int rbase = n0 + w*32 + tr*16 + quad*4;
    #pragma unroll
    for (int tc = 0; tc < 8; tc++) {
      int col = tc*16 + l15;
      #pragma unroll
      for (int g = 0; g < 4; g++) {
        int r = rbase + g;
        if (r < NN) {
          float v = acc[tr][tc][g] + bj[tc];
          float y = v > 0.f ? v : 0.f;
          sv[tc] += y; qv[tc] += y*y;
          A1[(size_t)r*FD + col] = f2bf(v);
        }
      }
    }
  }
  #pragma unroll
  for (int tc = 0; tc < 8; tc++) {
    sv[tc] += __shfl_xor(sv[tc], 16); qv[tc] += __shfl_xor(qv[tc], 16);
    sv[tc] += __shfl_xor(sv[tc], 32); qv[tc] += __shfl_xor(qv[tc], 32);
  }
  if (quad == 0) {
    #pragma unroll
    for (int tc = 0; tc < 8; tc++) {
      Sred[0][w][tc*16 + l15] = sv[tc];
      Sred[1][w][tc*16 + l15] = qv[tc];
    }
  }
  __syncthreads();
  if (tid < 128) {
    float s = Sred[0][0][tid] + Sred[0][1][tid] + Sred[0][2][tid] + Sred[0][3][tid];
    float q = Sred[1][0][tid] + Sred[1][1][tid] + Sred[1][2][tid] + Sred[1][3][tid];
    atomicAdd(&accSQ[ty*128 + tid], s);
    atomicAdd(&accSQ[256 + ty*128 + tid], q);
  }
}

// tiny: fold accumulated stats -> scale/shift; re-zero accumulators for next layer
__global__ __launch_bounds__(256) void k_bnfinal(float* __restrict__ accSQ,
                                                 const float* __restrict__ gu,
                                                 const float* __restrict__ bu,
                                                 const float* __restrict__ gi,
                                                 const float* __restrict__ bi,
                                                 float* __restrict__ bnsc,
                                                 float* __restrict__ bnsh) {
  int tid = threadIdx.x;
  int type = tid >> 7;            // 0=user, 1=item
  int c = tid & 127;
  float s = accSQ[tid];
  float q = accSQ[256 + tid];
  accSQ[tid] = 0.f;
  accSQ[256 + tid] = 0.f;
  float inv = 1.0f / (float)NN;
  float mean = s * inv;
  float var = q * inv - mean*mean;
  float rstd = rsqrtf(var + BNEPS);
  float g = type ? gi[c] : gu[c];
  float bb = type ? bi[c] : bu[c];
  float sc = rstd * g;
  bnsc[tid] = sc;
  bnsh[tid] = bb - mean * sc;
}

// BN-apply + fused mean-pool (batch ids sorted -> per-run register accumulation)
__global__ __launch_bounds__(256) void k_bnapply(const u16* __restrict__ newU,
                                                 const u16* __restrict__ newI,
                                                 const int* __restrict__ bu,
                                                 const int* __restrict__ bi,
                                                 const float* __restrict__ bnsc,
                                                 const float* __restrict__ bnsh,
                                                 const float* __restrict__ invcnt,
                                                 u16* __restrict__ xu,
                                                 u16* __restrict__ xi,
                                                 float* __restrict__ feats) {
  int type = blockIdx.y;          // 0=user, 1=item
  const u16* in = type ? newI : newU;
  const int* bt = type ? bi : bu;
  u16* out = type ? xi : xu;
  int tid = threadIdx.x;
  int c = tid & 127;
  int rh = tid >> 7;
  float sc = bnsc[type*128 + c];
  float sh = bnsh[type*128 + c];
  int rs = blockIdx.x*128 + rh*64;
  int re = rs + 64; if (re > NN) re = NN;
  if (rs >= re) return;
  int gcur = bt[rs];
  float acc = 0.f;
  for (int r = rs; r < re; r++) {
    int g = bt[r];
    if (g != gcur) {
      atomicAdd(&feats[(size_t)gcur*FD + c], acc * invcnt[gcur]);
      acc = 0.f; gcur = g;
    }
    float y = bf2f(in[(size_t)r*FD + c]);
    y = y > 0.f ? y : 0.f;
    float o = y * sc + sh;
    out[(size_t)r*FD + c] = f2bf(o);
    acc += o;
  }
  atomicAdd(&feats[(size_t)gcur*FD + c], acc * invcnt[gcur]);
}

__global__ __launch_bounds__(256) void k_heads(const float* __restrict__ feats,
                                               const float* __restrict__ fcW,
                                               const float* __restrict__ fcb,
                                               float* __restrict__ logits) {
  int idx = blockIdx.x*256 + threadIdx.x;
  if (idx >= LOGITS_N) return;
  int l = idx >> 13;
  int rem = idx & 8191;
  int g = rem >> 4;
  int c = rem & 15;
  const float* f = feats + ((size_t)l*NG + g)*FD;
  const float* w = fcW + ((size_t)l*NC + c)*FD;
  float s = 0.f;
  #pragma unroll
  for (int k = 0; k < FD; k += 4) {
    float4 fv = *(const float4*)(f + k);
    float4 wv = *(const float4*)(w + k);
    s += fv.x*wv.x + fv.y*wv.y + fv.z*wv.z + fv.w*wv.w;
  }
  logits[idx] = s + fcb[l*NC + c];
}

extern "C" void kernel_launch(void* const* d_in, const int* in_sizes, int n_in,
                              void* d_out, int out_size, void* d_ws, size_t ws_size,
                              hipStream_t stream) {
  const float* x_user   = (const float*)d_in[0];
  const float* x_item   = (const float*)d_in[1];
  const int*   eu2i     = (const int*)d_in[2];
  const int*   ei2u     = (const int*)d_in[3];
  const int*   bu       = (const int*)d_in[4];
  const int*   bi       = (const int*)d_in[5];
  const float* Wrel_u2i = (const float*)d_in[6];
  const float* Wroot_u2i= (const float*)d_in[7];
  const float* b_u2i    = (const float*)d_in[8];
  const float* Wrel_i2u = (const float*)d_in[9];
  const float* Wroot_i2u= (const float*)d_in[10];
  const float* b_i2u    = (const float*)d_in[11];
  const float* bn_g_user= (const float*)d_in[12];
  const float* bn_b_user= (const float*)d_in[13];
  const float* bn_g_item= (const float*)d_in[14];
  const float* bn_b_item= (const float*)d_in[15];
  const float* fcW      = (const float*)d_in[16];
  const float* fcb      = (const float*)d_in[17];

  char* ws = (char*)d_ws;
  int*   gcnt   = (int*)(ws + OFF_GCNT);
  int*   bcursor= (int*)(ws + OFF_BCUR);
  float* accSQ  = (float*)(ws + OFF_ACC);
  int2*  rowrange = (int2*)(ws + OFF_ROWRANGE);
  float* invcnt = (float*)(ws + OFF_INVCNT);
  float* bnsc   = (float*)(ws + OFF_BNSC);
  float* bnsh   = (float*)(ws + OFF_BNSH);
  u16*   WB     = (u16*)(ws + OFF_WB);
  int*   csrbin = (int*)(ws + OFF_CSR);
  u16*   aggI   = (u16*)(ws + OFF_AGGI);
  u16*   aggU   = (u16*)(ws + OFF_AGGU);
  u16*   xu     = (u16*)(ws + OFF_XU);
  u16*   xi     = (u16*)(ws + OFF_XI);
  u16*   xu0    = (u16*)(ws + OFF_XU0);
  u16*   xi0    = (u16*)(ws + OFF_XI0);
  float* fout   = (float*)d_out;
  float* featsAll = fout + LOGITS_N;

  hipMemsetAsync(ws, 0, MEMSET_BYTES, stream);
  hipMemsetAsync(featsAll, 0, (size_t)NL*NG*FD*sizeof(float), stream);
  k_hist_batch<<<NBLK, 256, 0, stream>>>(bu, bi, gcnt);
  k_bin<<<391, 256, 0, stream>>>(eu2i, ei2u, bcursor, csrbin);
  k_invcnt<<<1, 512, 0, stream>>>(gcnt, invcnt);
  k_csrbuild<<<NBUCK, 256, 0, stream>>>(bcursor, csrbin, rowrange);
  k_castX<<<12500, 256, 0, stream>>>(x_user, x_item, xu0, xi0);
  k_castW<<<768, 256, 0, stream>>>(Wrel_u2i, Wroot_u2i, Wrel_i2u, Wroot_i2u, WB);

  const u16* curU = xu0;
  const u16* curI = xi0;
  for (int l = 0; l < NL; l++) {
    k_gather<<<25000, 256, 0, stream>>>(curU, curI, rowrange, csrbin, aggI, aggU);
    k_gemm<<<dim3(NBLK,2), 256, 0, stream>>>(aggU, aggI, curU, curI,
                                             WB + (size_t)l*2*32768,
                                             b_i2u + l*FD, b_u2i + l*FD,
                                             accSQ);
    k_bnfinal<<<1, 256, 0, stream>>>(accSQ, bn_g_user, bn_b_user,
                                     bn_g_item, bn_b_item, bnsc, bnsh);
    k_bnapply<<<dim3(NBLK,2), 256, 0, stream>>>(aggU, aggI, bu, bi, bnsc, bnsh,
                                                invcnt, xu, xi,
                                                featsAll + (size_t)l*NG*FD);
    curU = xu; curI = xi;
  }
  k_heads<<<96, 256, 0, stream>>>(featsAll, fcW, fcb, fout);
}